// Round 7
// baseline (603.256 us; speedup 1.0000x reference)
//
#include <hip/hip_runtime.h>
#include <hip/hip_bf16.h>

typedef __attribute__((ext_vector_type(8))) short bf16x8;
typedef __attribute__((ext_vector_type(4))) float f32x4;
typedef __attribute__((ext_vector_type(4))) unsigned int uint32x4;

#define N_TOK 1024
#define HEADS 8
#define DIM_HEAD 64
#define BATCH 8
#define DIMM 512
#define INNER 512
#define QKV_COLS 1536

#define MFMA16 __builtin_amdgcn_mfma_f32_16x16x32_bf16

__device__ inline short f2bf(float f) {
  union { float f; unsigned u; } v;
  v.f = f;
  unsigned r = v.u + 0x7fffu + ((v.u >> 16) & 1u);  // RNE
  return (short)(r >> 16);
}

__device__ inline unsigned pack2bf(float a, float b) {
  return ((unsigned)(unsigned short)f2bf(a)) | (((unsigned)(unsigned short)f2bf(b)) << 16);
}

// LDS-only barrier: orders LDS across waves WITHOUT draining global stores
// (__syncthreads emits s_waitcnt vmcnt(0) which stalls on the HBM write stream).
__device__ inline void lds_barrier() {
  asm volatile("s_waitcnt lgkmcnt(0)" ::: "memory");
  __builtin_amdgcn_s_barrier();
  asm volatile("" ::: "memory");
}

// ---------------- elementwise fp32 -> bf16 ----------------
__global__ void cvt_bf16_kernel(const float* __restrict__ in, short* __restrict__ out, int n) {
  int i = (blockIdx.x * 256 + threadIdx.x) * 4;
  if (i >= n) return;
  float4 v = *(const float4*)&in[i];
  short4 o;
  o.x = f2bf(v.x); o.y = f2bf(v.y); o.z = f2bf(v.z); o.w = f2bf(v.w);
  *(short4*)&out[i] = o;
}

// ---------------- transpose + convert: W[K][Nc] -> Wt[Nc][K] bf16 ----------------
__global__ void tr_cvt_kernel(const float* __restrict__ W, short* __restrict__ Wt, int K, int Nc) {
  int id = blockIdx.x * 256 + threadIdx.x;
  if (id >= K * Nc) return;
  int n = id % Nc, k = id / Nc;
  Wt[n * K + k] = f2bf(W[id]);
}

// ------- fused EXP bias table: bias2e[idx][h] = exp(rel[idx][h] + 0.01*exp(-factor_h*dis)) -------
__global__ void bias2e_kernel(const float* __restrict__ rel, const float* __restrict__ headsita,
                              float* __restrict__ bias2e) {
  int e = blockIdx.x * 256 + threadIdx.x;
  if (e >= 3969 * HEADS) return;
  int idx = e >> 3, h = e & 7;
  int dr = idx / 63 - 31;
  int dc = idx % 63 - 31;
  float th = headsita[h];
  float factor = 1.f / (2.f * th * th + 1e-10f);
  float dis = (float)(dr * dr + dc * dc) * (1.0f / 1024.0f);
  bias2e[e] = __expf(rel[e] + 0.01f * __expf(-factor * dis));
}

// ---------------- V transpose: qkv V-slice -> Vt[bh][64 d][1024 j] ----------------
__global__ __launch_bounds__(256)
void v_tr_kernel(const short* __restrict__ qkv, short* __restrict__ Vt) {
  __shared__ short T[64][72];
  int t = threadIdx.x;
  int j0 = blockIdx.x * 64;
  int bh = blockIdx.y;
  int b = bh >> 3, h = bh & 7;
  #pragma unroll
  for (int c = 0; c < 2; ++c) {
    int idn = c * 256 + t;
    int j = idn >> 3, dc = (idn & 7) * 8;
    *(int4*)&T[j][dc] =
      *(const int4*)&qkv[(size_t)(b * N_TOK + j0 + j) * QKV_COLS + 2 * INNER + h * DIM_HEAD + dc];
  }
  lds_barrier();
  #pragma unroll
  for (int c = 0; c < 2; ++c) {
    int idn = c * 256 + t;
    int d = idn >> 3, je = (idn & 7) * 8;
    short tmp[8];
    #pragma unroll
    for (int e = 0; e < 8; ++e) tmp[e] = T[je + e][d];
    *(int4*)&Vt[((size_t)bh * 64 + d) * N_TOK + j0 + je] = *(int4*)tmp;
  }
}

// ---------------- bf16 MFMA GEMM with register prefetch + LDS-only barriers ----------------
template<int OUT_BF16, int ADD_BIAS>
__global__ __launch_bounds__(256)
void gemm_kernel(const short* __restrict__ A, const short* __restrict__ Bt,
                 void* __restrict__ C, const float* __restrict__ bias,
                 int M, int Nc, int K)
{
  __shared__ short Ash[128][40];
  __shared__ short Bsh[128][40];
  const int t = threadIdx.x;
  const int lane = t & 63, wave = t >> 6;
  const int wm = wave >> 1, wn = wave & 1;
  const int m0 = blockIdx.y * 128, n0 = blockIdx.x * 128;
  f32x4 acc[4][4] = {};
  int4 sa[2], sb[2];
  #pragma unroll
  for (int c = 0; c < 2; ++c) {
    int id = c * 256 + t, row = id >> 2, kc = (id & 3) * 8;
    sa[c] = *(const int4*)&A[(size_t)(m0 + row) * K + kc];
    sb[c] = *(const int4*)&Bt[(size_t)(n0 + row) * K + kc];
  }
  for (int k0 = 0; k0 < K; k0 += 32) {
    lds_barrier();
    #pragma unroll
    for (int c = 0; c < 2; ++c) {
      int id = c * 256 + t, row = id >> 2, kc = (id & 3) * 8;
      *(int4*)&Ash[row][kc] = sa[c];
      *(int4*)&Bsh[row][kc] = sb[c];
    }
    lds_barrier();
    if (k0 + 32 < K) {
      #pragma unroll
      for (int c = 0; c < 2; ++c) {
        int id = c * 256 + t, row = id >> 2, kc = (id & 3) * 8;
        sa[c] = *(const int4*)&A[(size_t)(m0 + row) * K + k0 + 32 + kc];
        sb[c] = *(const int4*)&Bt[(size_t)(n0 + row) * K + k0 + 32 + kc];
      }
    }
    bf16x8 af[4], bfr[4];
    #pragma unroll
    for (int m = 0; m < 4; ++m)
      af[m] = *(const bf16x8*)&Ash[wm*64 + m*16 + (lane & 15)][(lane >> 4) * 8];
    #pragma unroll
    for (int n = 0; n < 4; ++n)
      bfr[n] = *(const bf16x8*)&Bsh[wn*64 + n*16 + (lane & 15)][(lane >> 4) * 8];
    #pragma unroll
    for (int m = 0; m < 4; ++m)
      #pragma unroll
      for (int n = 0; n < 4; ++n)
        acc[m][n] = MFMA16(af[m], bfr[n], acc[m][n], 0, 0, 0);
  }
  const int r0 = (lane >> 4) * 4, c0 = lane & 15;
  #pragma unroll
  for (int m = 0; m < 4; ++m)
    #pragma unroll
    for (int n = 0; n < 4; ++n) {
      int col = n0 + wn*64 + n*16 + c0;
      float bv = ADD_BIAS ? bias[col] : 0.f;
      #pragma unroll
      for (int r = 0; r < 4; ++r) {
        int row = m0 + wm*64 + m*16 + r0 + r;
        float v = acc[m][n][r] + bv;
        if (OUT_BF16) ((short*)C)[(size_t)row * Nc + col] = f2bf(v);
        else          ((float*)C)[(size_t)row * Nc + col] = v;
      }
    }
}

// ---------------- fused attention v7: two-pass online softmax, LDS-only barriers ----------------
// block = (b,h,16 q-rows), 4 waves, swapped mfma(K,Q) (lane owns S^T[j][i=cl]).
// Pass 1: online (max, sum, biased-sum) with deep K prefetch, ~tiny regs.
// Pass 2: per 256-j chunk recompute S, emit out2 (staged full-line stores), pack P
// (wave-private LDS), PV with direct Vt frags. No vmcnt-draining barriers anywhere.
__global__ __launch_bounds__(256, 5)
void attn_kernel(const short* __restrict__ qkv,
                 const short* __restrict__ Vt,        // [bh][64][1024]
                 const float* __restrict__ bias2e,    // [3969][8] = exp(rel + 0.01*gauss)
                 const int* __restrict__ rpe_p,
                 float* __restrict__ out2,            // softmax(dots0) [B,H,N,N]
                 short* __restrict__ Obuf)            // [B*N][512] bf16
{
  __shared__ float stage[256 * 17];      // 17408 B: out2 chunk transpose; buf in epilogue
  __shared__ short Pp[4][16 * 68];       // 8704 B: wave-private P chunk [16 i][64 j] pitch 68
  __shared__ float4 red4[4][16];         // 1024 B: (m, s0, s1) reduce

  const int t = threadIdx.x;
  const int lane = t & 63, wv = t >> 6;
  const int rg = lane >> 4, cl = lane & 15;

  const int id = blockIdx.x;                 // XCD-swizzled (bijective)
  const int bh = (id & 7) * 8 + ((id >> 3) & 7);
  const int i0 = (id >> 6) * 16;
  const int b = bh >> 3, h = bh & 7;
  const size_t rowbase = (size_t)b * N_TOK;
  const int userpe = rpe_p[0];

  // ---- Q fragments (B-operand) ----
  const size_t qoff = (rowbase + i0 + cl) * QKV_COLS + h * DIM_HEAD;
  const bf16x8 qf0 = *(const bf16x8*)&qkv[qoff + rg * 8];
  const bf16x8 qf1 = *(const bf16x8*)&qkv[qoff + 32 + rg * 8];

  const short* krow = qkv + (rowbase + wv * 16 + cl) * QKV_COLS + INNER + h * DIM_HEAD + rg * 8;
  const size_t KSTR = (size_t)64 * QKV_COLS;

  const int i_row = i0 + cl;
  const int ri = i_row >> 5, ci = i_row & 31;
  const int jbase = wv * 16 + rg * 4;
  const float* bt = bias2e + h;

  // ================= pass 1: online (m, s0, s1) =================
  float m = -1e30f, s0 = 0.f, s1 = 0.f;

  bf16x8 c00 = *(const bf16x8*)&krow[0];
  bf16x8 c01 = *(const bf16x8*)&krow[32];
  bf16x8 c10 = *(const bf16x8*)&krow[KSTR];
  bf16x8 c11 = *(const bf16x8*)&krow[KSTR + 32];

  #pragma unroll
  for (int g = 0; g < 8; ++g) {
    bf16x8 n00, n01, n10, n11;
    if (g < 7) {
      n00 = *(const bf16x8*)&krow[(size_t)(2*g+2) * KSTR];
      n01 = *(const bf16x8*)&krow[(size_t)(2*g+2) * KSTR + 32];
      n10 = *(const bf16x8*)&krow[(size_t)(2*g+3) * KSTR];
      n11 = *(const bf16x8*)&krow[(size_t)(2*g+3) * KSTR + 32];
    }
    #pragma unroll
    for (int hf = 0; hf < 2; ++hf) {
      const int tj = 2*g + hf;
      f32x4 z = (f32x4){0.f, 0.f, 0.f, 0.f};
      z = MFMA16(hf ? c10 : c00, qf0, z, 0, 0, 0);
      z = MFMA16(hf ? c11 : c01, qf1, z, 0, 0, 0);
      float z0 = z[0]*0.125f, z1 = z[1]*0.125f, z2 = z[2]*0.125f, z3 = z[3]*0.125f;
      float tm = fmaxf(fmaxf(z0, z1), fmaxf(z2, z3));
      float nm = fmaxf(m, tm);
      float scl = __expf(m - nm);
      float e0 = __expf(z0 - nm), e1 = __expf(z1 - nm);
      float e2 = __expf(z2 - nm), e3 = __expf(z3 - nm);
      float b0 = 1.f, b1 = 1.f, b2 = 1.f, b3 = 1.f;
      if (userpe) {
        int j0 = tj * 64 + jbase;
        b0 = bt[((ri - ((j0+0) >> 5)) * 63 + (ci - ((j0+0) & 31)) + 1984) * 8];
        b1 = bt[((ri - ((j0+1) >> 5)) * 63 + (ci - ((j0+1) & 31)) + 1984) * 8];
        b2 = bt[((ri - ((j0+2) >> 5)) * 63 + (ci - ((j0+2) & 31)) + 1984) * 8];
        b3 = bt[((ri - ((j0+3) >> 5)) * 63 + (ci - ((j0+3) & 31)) + 1984) * 8];
      }
      s0 = s0 * scl + ((e0 + e1) + (e2 + e3));
      s1 = s1 * scl + ((e0*b0 + e1*b1) + (e2*b2 + e3*b3));
      m = nm;
    }
    if (g < 7) { c00 = n00; c01 = n01; c10 = n10; c11 = n11; }
  }

  // ---- merge across rg (butterfly 16, 32) ----
  #pragma unroll
  for (int off = 16; off <= 32; off <<= 1) {
    float om = __shfl_xor(m, off);
    float q0 = __shfl_xor(s0, off);
    float q1 = __shfl_xor(s1, off);
    float M = fmaxf(m, om);
    float wa = __expf(m - M), wb = __expf(om - M);
    s0 = s0 * wa + q0 * wb;
    s1 = s1 * wa + q1 * wb;
    m = M;
  }
  if (lane < 16) red4[wv][lane] = make_float4(m, s0, s1, 0.f);
  lds_barrier();
  {
    float4 a0 = red4[0][cl], a1 = red4[1][cl], a2 = red4[2][cl], a3 = red4[3][cl];
    float M = fmaxf(fmaxf(a0.x, a1.x), fmaxf(a2.x, a3.x));
    float w0 = __expf(a0.x - M), w1 = __expf(a1.x - M);
    float w2 = __expf(a2.x - M), w3 = __expf(a3.x - M);
    s0 = a0.y*w0 + a1.y*w1 + a2.y*w2 + a3.y*w3;
    s1 = a0.z*w0 + a1.z*w1 + a2.z*w2 + a3.z*w3;
    m = M;
  }
  const float iv0 = 1.f / s0;
  const float iv1 = 1.f / s1;

  // ================= pass 2: recompute per chunk; out2 + P + PV =================
  const size_t o2base = ((size_t)(b * HEADS + h) * N_TOK + i0) * N_TOK;
  const size_t vtb = (size_t)bh * 64;
  short* pw = &Pp[wv][0];

  f32x4 oacc0 = (f32x4){0.f,0.f,0.f,0.f};
  f32x4 oacc1 = (f32x4){0.f,0.f,0.f,0.f};
  f32x4 oacc2 = (f32x4){0.f,0.f,0.f,0.f};
  f32x4 oacc3 = (f32x4){0.f,0.f,0.f,0.f};

  auto proc2 = [&](bf16x8 k0, bf16x8 k1, int tj, int tt) -> uint2 {
    f32x4 z = (f32x4){0.f, 0.f, 0.f, 0.f};
    z = MFMA16(k0, qf0, z, 0, 0, 0);
    z = MFMA16(k1, qf1, z, 0, 0, 0);
    float z0 = z[0]*0.125f, z1 = z[1]*0.125f, z2 = z[2]*0.125f, z3 = z[3]*0.125f;
    float e0 = __expf(z0 - m), e1 = __expf(z1 - m);
    float e2 = __expf(z2 - m), e3 = __expf(z3 - m);
    int rowb = tt * 64 + wv * 16 + rg * 4;
    stage[(rowb+0)*17 + cl] = e0 * iv0;
    stage[(rowb+1)*17 + cl] = e1 * iv0;
    stage[(rowb+2)*17 + cl] = e2 * iv0;
    stage[(rowb+3)*17 + cl] = e3 * iv0;
    float b0 = 1.f, b1 = 1.f, b2 = 1.f, b3 = 1.f;
    if (userpe) {
      int j0 = tj * 64 + jbase;
      b0 = bt[((ri - ((j0+0) >> 5)) * 63 + (ci - ((j0+0) & 31)) + 1984) * 8];
      b1 = bt[((ri - ((j0+1) >> 5)) * 63 + (ci - ((j0+1) & 31)) + 1984) * 8];
      b2 = bt[((ri - ((j0+2) >> 5)) * 63 + (ci - ((j0+2) & 31)) + 1984) * 8];
      b3 = bt[((ri - ((j0+3) >> 5)) * 63 + (ci - ((j0+3) & 31)) + 1984) * 8];
    }
    uint2 pk;
    pk.x = pack2bf(e0*b0*iv1, e1*b1*iv1);
    pk.y = pack2bf(e2*b2*iv1, e3*b3*iv1);
    return pk;
  };

  #pragma unroll
  for (int c = 0; c < 4; ++c) {
    // K loads: 4 tiles, issued together
    bf16x8 k00 = *(const bf16x8*)&krow[(size_t)(c*4+0) * KSTR];
    bf16x8 k01 = *(const bf16x8*)&krow[(size_t)(c*4+0) * KSTR + 32];
    bf16x8 k10 = *(const bf16x8*)&krow[(size_t)(c*4+1) * KSTR];
    bf16x8 k11 = *(const bf16x8*)&krow[(size_t)(c*4+1) * KSTR + 32];
    bf16x8 k20 = *(const bf16x8*)&krow[(size_t)(c*4+2) * KSTR];
    bf16x8 k21 = *(const bf16x8*)&krow[(size_t)(c*4+2) * KSTR + 32];
    bf16x8 k30 = *(const bf16x8*)&krow[(size_t)(c*4+3) * KSTR];
    bf16x8 k31 = *(const bf16x8*)&krow[(size_t)(c*4+3) * KSTR + 32];

    uint2 pk0 = proc2(k00, k01, c*4+0, 0);
    uint2 pk1 = proc2(k10, k11, c*4+1, 1);
    uint2 pk2 = proc2(k20, k21, c*4+2, 2);
    uint2 pk3 = proc2(k30, k31, c*4+3, 3);

    // P writes (wave-private region: no barrier needed for these)
    *(uint2*)&pw[cl*68 + 0*16 + rg*4] = pk0;
    *(uint2*)&pw[cl*68 + 1*16 + rg*4] = pk1;
    *(uint2*)&pw[cl*68 + 2*16 + rg*4] = pk2;
    *(uint2*)&pw[cl*68 + 3*16 + rg*4] = pk3;

    // Vt fragment loads for this chunk (independent -> fly under barrier+stores)
    const int vrow = wv * 16 + (rg & 1) * 8;
    const int rsel = (rg >> 1) * 64;
    bf16x8 va00 = *(const bf16x8*)&Vt[(vtb + 0*16 + cl) * N_TOK + c*256 + 0*128 + rsel + vrow];
    bf16x8 va01 = *(const bf16x8*)&Vt[(vtb + 1*16 + cl) * N_TOK + c*256 + 0*128 + rsel + vrow];
    bf16x8 va02 = *(const bf16x8*)&Vt[(vtb + 2*16 + cl) * N_TOK + c*256 + 0*128 + rsel + vrow];
    bf16x8 va03 = *(const bf16x8*)&Vt[(vtb + 3*16 + cl) * N_TOK + c*256 + 0*128 + rsel + vrow];
    bf16x8 va10 = *(const bf16x8*)&Vt[(vtb + 0*16 + cl) * N_TOK + c*256 + 1*128 + rsel + vrow];
    bf16x8 va11 = *(const bf16x8*)&Vt[(vtb + 1*16 + cl) * N_TOK + c*256 + 1*128 + rsel + vrow];
    bf16x8 va12 = *(const bf16x8*)&Vt[(vtb + 2*16 + cl) * N_TOK + c*256 + 1*128 + rsel + vrow];
    bf16x8 va13 = *(const bf16x8*)&Vt[(vtb + 3*16 + cl) * N_TOK + c*256 + 1*128 + rsel + vrow];

    lds_barrier();   // stage chunk visible to all waves

    // out2 stores: full-line contiguous (256B/instr/wave), plain cached
    #pragma unroll
    for (int k = 0; k < 4; ++k) {
      int row = wv * 4 + k;
      #pragma unroll
      for (int e4 = 0; e4 < 4; ++e4) {
        float v = stage[(e4 * 64 + lane) * 17 + row];
        out2[o2base + (size_t)row * N_TOK + c * 256 + e4 * 64 + lane] = v;
      }
    }

    // PV: 2 mfma steps over this wave's 64 chunk-j's
    {
      uint2 qa = *(const uint2*)&pw[cl*68 + 0*32 + rg*8];
      uint2 qb = *(const uint2*)&pw[cl*68 + 0*32 + rg*8 + 4];
      union { uint32x4 u; bf16x8 v; } pb;
      pb.u = (uint32x4){qa.x, qa.y, qb.x, qb.y};
      oacc0 = MFMA16(va00, pb.v, oacc0, 0, 0, 0);
      oacc1 = MFMA16(va01, pb.v, oacc1, 0, 0, 0);
      oacc2 = MFMA16(va02, pb.v, oacc2, 0, 0, 0);
      oacc3 = MFMA16(va03, pb.v, oacc3, 0, 0, 0);
    }
    {
      uint2 qa = *(const uint2*)&pw[cl*68 + 1*32 + rg*8];
      uint2 qb = *(const uint2*)&pw[cl*68 + 1*32 + rg*8 + 4];
      union { uint32x4 u; bf16x8 v; } pb;
      pb.u = (uint32x4){qa.x, qa.y, qb.x, qb.y};
      oacc0 = MFMA16(va10, pb.v, oacc0, 0, 0, 0);
      oacc1 = MFMA16(va11, pb.v, oacc1, 0, 0, 0);
      oacc2 = MFMA16(va12, pb.v, oacc2, 0, 0, 0);
      oacc3 = MFMA16(va13, pb.v, oacc3, 0, 0, 0);
    }

    lds_barrier();   // stage/P reads complete before next chunk overwrites
  }

  // ================= epilogue: cross-wave O reduce + Obuf =================
  float* buf = stage;                       // [4][16][65] f32 (16640 B <= 17408)
  #pragma unroll
  for (int r = 0; r < 4; ++r) {
    buf[wv*1040 + cl*65 +  0 + rg*4 + r] = oacc0[r];
    buf[wv*1040 + cl*65 + 16 + rg*4 + r] = oacc1[r];
    buf[wv*1040 + cl*65 + 32 + rg*4 + r] = oacc2[r];
    buf[wv*1040 + cl*65 + 48 + rg*4 + r] = oacc3[r];
  }
  lds_barrier();

  const int i_ = t >> 4, dq = t & 15;
  float o[4];
  #pragma unroll
  for (int k = 0; k < 4; ++k) {
    int d = dq * 4 + k;
    o[k] = buf[0*1040 + i_*65 + d] + buf[1*1040 + i_*65 + d]
         + buf[2*1040 + i_*65 + d] + buf[3*1040 + i_*65 + d];
  }
  short4 os;
  os.x = f2bf(o[0]); os.y = f2bf(o[1]); os.z = f2bf(o[2]); os.w = f2bf(o[3]);
  *(short4*)&Obuf[(rowbase + i0 + i_) * INNER + h * DIM_HEAD + dq * 4] = os;
}

extern "C" void kernel_launch(void* const* d_in, const int* in_sizes, int n_in,
                              void* d_out, int out_size, void* d_ws, size_t ws_size,
                              hipStream_t stream) {
  const float* x    = (const float*)d_in[0];
  const float* Wqkv = (const float*)d_in[1];
  const float* Wout = (const float*)d_in[2];
  const float* bout = (const float*)d_in[3];
  const float* rel  = (const float*)d_in[4];
  const float* sita = (const float*)d_in[5];
  const int*   rpe  = (const int*)d_in[6];

  char* ws = (char*)d_ws;
  short* xb     = (short*)(ws);                 //  8 MB  x bf16 (dead after gemm1)
  short* WqT    = (short*)(ws + 8388608);       //  1.5MB W_qkv^T (dead after gemm1)
  short* WoT    = (short*)(ws + 9961472);       //  0.5MB W_out^T
  short* qkv    = (short*)(ws + 10485760);      // 24 MB  qkv bf16 [8192][1536]
  short* Obuf   = (short*)(ws + 35651584);      //  8 MB  attn-out bf16 [8192][512]
  short* Vt     = (short*)(ws);                 //  8 MB  V^T [64][64][1024] (reuses xb)
  float* bias2e = (float*)(ws + 8388608);       // 127 KB exp'd fused bias (reuses WqT)

  float* out1 = (float*)d_out;
  float* out2 = out1 + (size_t)BATCH * N_TOK * DIMM;

  hipLaunchKernelGGL(cvt_bf16_kernel, dim3(4096), dim3(256), 0, stream,
                     x, xb, BATCH * N_TOK * DIMM);
  hipLaunchKernelGGL(tr_cvt_kernel, dim3((512 * 1536 + 255) / 256), dim3(256), 0, stream,
                     Wqkv, WqT, 512, 1536);
  hipLaunchKernelGGL(tr_cvt_kernel, dim3((512 * 512 + 255) / 256), dim3(256), 0, stream,
                     Wout, WoT, 512, 512);
  hipLaunchKernelGGL((gemm_kernel<1, 0>), dim3(12, 64), dim3(256), 0, stream,
                     xb, WqT, (void*)qkv, (const float*)nullptr, 8192, 1536, 512);
  // xb / WqT regions are dead now -> Vt / bias2e may overwrite them
  hipLaunchKernelGGL(bias2e_kernel, dim3((3969 * HEADS + 255) / 256), dim3(256), 0, stream,
                     rel, sita, bias2e);
  hipLaunchKernelGGL(v_tr_kernel, dim3(16, 64), dim3(256), 0, stream, qkv, Vt);
  hipLaunchKernelGGL(attn_kernel, dim3(4096), dim3(256), 0, stream,
                     qkv, Vt, bias2e, rpe, out2, Obuf);
  hipLaunchKernelGGL((gemm_kernel<0, 1>), dim3(4, 64), dim3(256), 0, stream,
                     Obuf, WoT, d_out, bout, 8192, 512, 512);
}

// Round 8
// 363.369 us; speedup vs baseline: 1.6602x; 1.6602x over previous
//
#include <hip/hip_runtime.h>
#include <hip/hip_bf16.h>

typedef __attribute__((ext_vector_type(8))) short bf16x8;
typedef __attribute__((ext_vector_type(4))) float f32x4;
typedef __attribute__((ext_vector_type(4))) unsigned int uint32x4;

#define N_TOK 1024
#define HEADS 8
#define DIM_HEAD 64
#define BATCH 8
#define DIMM 512
#define INNER 512
#define QKV_COLS 1536

#define MFMA16 __builtin_amdgcn_mfma_f32_16x16x32_bf16

__device__ inline short f2bf(float f) {
  union { float f; unsigned u; } v;
  v.f = f;
  unsigned r = v.u + 0x7fffu + ((v.u >> 16) & 1u);  // RNE
  return (short)(r >> 16);
}

__device__ inline unsigned pack2bf(float a, float b) {
  return ((unsigned)(unsigned short)f2bf(a)) | (((unsigned)(unsigned short)f2bf(b)) << 16);
}

// LDS-only barrier: orders LDS across waves WITHOUT draining global stores
// (__syncthreads emits s_waitcnt vmcnt(0) which stalls on the HBM write stream).
__device__ inline void lds_barrier() {
  asm volatile("s_waitcnt lgkmcnt(0)" ::: "memory");
  __builtin_amdgcn_s_barrier();
  asm volatile("" ::: "memory");
}

// ---------------- elementwise fp32 -> bf16 ----------------
__global__ void cvt_bf16_kernel(const float* __restrict__ in, short* __restrict__ out, int n) {
  int i = (blockIdx.x * 256 + threadIdx.x) * 4;
  if (i >= n) return;
  float4 v = *(const float4*)&in[i];
  short4 o;
  o.x = f2bf(v.x); o.y = f2bf(v.y); o.z = f2bf(v.z); o.w = f2bf(v.w);
  *(short4*)&out[i] = o;
}

// ---------------- transpose + convert: W[K][Nc] -> Wt[Nc][K] bf16 ----------------
__global__ void tr_cvt_kernel(const float* __restrict__ W, short* __restrict__ Wt, int K, int Nc) {
  int id = blockIdx.x * 256 + threadIdx.x;
  if (id >= K * Nc) return;
  int n = id % Nc, k = id / Nc;
  Wt[n * K + k] = f2bf(W[id]);
}

// ------- fused EXP bias table: bias2e[idx][h] = exp(rel[idx][h] + 0.01*exp(-factor_h*dis)) -------
__global__ void bias2e_kernel(const float* __restrict__ rel, const float* __restrict__ headsita,
                              float* __restrict__ bias2e) {
  int e = blockIdx.x * 256 + threadIdx.x;
  if (e >= 3969 * HEADS) return;
  int idx = e >> 3, h = e & 7;
  int dr = idx / 63 - 31;
  int dc = idx % 63 - 31;
  float th = headsita[h];
  float factor = 1.f / (2.f * th * th + 1e-10f);
  float dis = (float)(dr * dr + dc * dc) * (1.0f / 1024.0f);
  bias2e[e] = __expf(rel[e] + 0.01f * __expf(-factor * dis));
}

// ---------------- V transpose: qkv V-slice -> Vt[bh][64 d][1024 j] ----------------
__global__ __launch_bounds__(256)
void v_tr_kernel(const short* __restrict__ qkv, short* __restrict__ Vt) {
  __shared__ short T[64][72];
  int t = threadIdx.x;
  int j0 = blockIdx.x * 64;
  int bh = blockIdx.y;
  int b = bh >> 3, h = bh & 7;
  #pragma unroll
  for (int c = 0; c < 2; ++c) {
    int idn = c * 256 + t;
    int j = idn >> 3, dc = (idn & 7) * 8;
    *(int4*)&T[j][dc] =
      *(const int4*)&qkv[(size_t)(b * N_TOK + j0 + j) * QKV_COLS + 2 * INNER + h * DIM_HEAD + dc];
  }
  lds_barrier();
  #pragma unroll
  for (int c = 0; c < 2; ++c) {
    int idn = c * 256 + t;
    int d = idn >> 3, je = (idn & 7) * 8;
    short tmp[8];
    #pragma unroll
    for (int e = 0; e < 8; ++e) tmp[e] = T[je + e][d];
    *(int4*)&Vt[((size_t)bh * 64 + d) * N_TOK + j0 + je] = *(int4*)tmp;
  }
}

// ---------------- bf16 MFMA GEMM with register prefetch + LDS-only barriers ----------------
template<int OUT_BF16, int ADD_BIAS>
__global__ __launch_bounds__(256)
void gemm_kernel(const short* __restrict__ A, const short* __restrict__ Bt,
                 void* __restrict__ C, const float* __restrict__ bias,
                 int M, int Nc, int K)
{
  __shared__ short Ash[128][40];
  __shared__ short Bsh[128][40];
  const int t = threadIdx.x;
  const int lane = t & 63, wave = t >> 6;
  const int wm = wave >> 1, wn = wave & 1;
  const int m0 = blockIdx.y * 128, n0 = blockIdx.x * 128;
  f32x4 acc[4][4] = {};
  int4 sa[2], sb[2];
  #pragma unroll
  for (int c = 0; c < 2; ++c) {
    int id = c * 256 + t, row = id >> 2, kc = (id & 3) * 8;
    sa[c] = *(const int4*)&A[(size_t)(m0 + row) * K + kc];
    sb[c] = *(const int4*)&Bt[(size_t)(n0 + row) * K + kc];
  }
  for (int k0 = 0; k0 < K; k0 += 32) {
    lds_barrier();
    #pragma unroll
    for (int c = 0; c < 2; ++c) {
      int id = c * 256 + t, row = id >> 2, kc = (id & 3) * 8;
      *(int4*)&Ash[row][kc] = sa[c];
      *(int4*)&Bsh[row][kc] = sb[c];
    }
    lds_barrier();
    if (k0 + 32 < K) {
      #pragma unroll
      for (int c = 0; c < 2; ++c) {
        int id = c * 256 + t, row = id >> 2, kc = (id & 3) * 8;
        sa[c] = *(const int4*)&A[(size_t)(m0 + row) * K + k0 + 32 + kc];
        sb[c] = *(const int4*)&Bt[(size_t)(n0 + row) * K + k0 + 32 + kc];
      }
    }
    bf16x8 af[4], bfr[4];
    #pragma unroll
    for (int m = 0; m < 4; ++m)
      af[m] = *(const bf16x8*)&Ash[wm*64 + m*16 + (lane & 15)][(lane >> 4) * 8];
    #pragma unroll
    for (int n = 0; n < 4; ++n)
      bfr[n] = *(const bf16x8*)&Bsh[wn*64 + n*16 + (lane & 15)][(lane >> 4) * 8];
    #pragma unroll
    for (int m = 0; m < 4; ++m)
      #pragma unroll
      for (int n = 0; n < 4; ++n)
        acc[m][n] = MFMA16(af[m], bfr[n], acc[m][n], 0, 0, 0);
  }
  const int r0 = (lane >> 4) * 4, c0 = lane & 15;
  #pragma unroll
  for (int m = 0; m < 4; ++m)
    #pragma unroll
    for (int n = 0; n < 4; ++n) {
      int col = n0 + wn*64 + n*16 + c0;
      float bv = ADD_BIAS ? bias[col] : 0.f;
      #pragma unroll
      for (int r = 0; r < 4; ++r) {
        int row = m0 + wm*64 + m*16 + r0 + r;
        float v = acc[m][n][r] + bv;
        if (OUT_BF16) ((short*)C)[(size_t)row * Nc + col] = f2bf(v);
        else          ((float*)C)[(size_t)row * Nc + col] = v;
      }
    }
}

// ---------------- fused attention v8: R6 structure + LDS-only barriers ----------------
// block = (b,h,16 q-rows), 4 waves. mfma(K,Q) => lane owns S^T[j][i=cl]:
// j = tj*64 + wv*16 + rg*4 + r, i = i0+cl. Single pass; K read once; sc[16] in regs.
// ONLY change vs R6 (253us, ideal write counters): __syncthreads -> lds_barrier
// (no vmcnt(0) drain; out2 store stream overlaps subsequent compute).
__global__ __launch_bounds__(256, 4)
void attn_kernel(const short* __restrict__ qkv,
                 const short* __restrict__ Vt,        // [bh][64][1024]
                 const float* __restrict__ bias2e,    // [3969][8] = exp(rel + 0.01*gauss)
                 const int* __restrict__ rpe_p,
                 float* __restrict__ out2,            // softmax(dots0) [B,H,N,N]
                 short* __restrict__ Obuf)            // [B*N][512] bf16
{
  __shared__ __align__(16) char arena[33024];  // time-shared: stage / P_lds / buf
  __shared__ float red0[4][16];
  __shared__ float red1[4][16];

  const int t = threadIdx.x;
  const int lane = t & 63, wv = t >> 6;
  const int rg = lane >> 4, cl = lane & 15;

  const int id = blockIdx.x;                 // XCD-swizzled (bijective): same-bh -> same XCD
  const int bh = (id & 7) * 8 + ((id >> 3) & 7);
  const int i0 = (id >> 6) * 16;
  const int b = bh >> 3, h = bh & 7;
  const size_t rowbase = (size_t)b * N_TOK;

  // ---- Q fragments (B-operand): Q[i0+cl][rg*8 / +32] ----
  const size_t qoff = (rowbase + i0 + cl) * QKV_COLS + h * DIM_HEAD;
  const bf16x8 qf0 = *(const bf16x8*)&qkv[qoff + rg * 8];
  const bf16x8 qf1 = *(const bf16x8*)&qkv[qoff + 32 + rg * 8];

  // ---- QK^T (swapped): sc[tj] rows j = tj*64 + wv*16 + rg*4 + r, col i = i0+cl ----
  const short* krow = qkv + (rowbase + wv * 16 + cl) * QKV_COLS + INNER + h * DIM_HEAD + rg * 8;
  const size_t KSTR = (size_t)64 * QKV_COLS;   // j-tile stride (shorts)
  f32x4 sc[16];
  bf16x8 a0 = *(const bf16x8*)&krow[0];
  bf16x8 a1 = *(const bf16x8*)&krow[32];
  #pragma unroll
  for (int tj = 0; tj < 16; ++tj) {
    bf16x8 n0, n1;
    if (tj < 15) {
      n0 = *(const bf16x8*)&krow[(tj + 1) * KSTR];
      n1 = *(const bf16x8*)&krow[(tj + 1) * KSTR + 32];
    }
    f32x4 z = (f32x4){0.f, 0.f, 0.f, 0.f};
    z = MFMA16(a0, qf0, z, 0, 0, 0);
    z = MFMA16(a1, qf1, z, 0, 0, 0);
    sc[tj] = z;
    a0 = n0; a1 = n1;
  }

  // ---- scale + softmax0 (per-lane scalar: row i = i0+cl fixed) ----
  float m = -1e30f;
  #pragma unroll
  for (int tj = 0; tj < 16; ++tj)
    #pragma unroll
    for (int r = 0; r < 4; ++r) {
      sc[tj][r] *= 0.125f;
      m = fmaxf(m, sc[tj][r]);
    }
  m = fmaxf(m, __shfl_xor(m, 16));
  m = fmaxf(m, __shfl_xor(m, 32));
  if (lane < 16) red0[wv][lane] = m;
  lds_barrier();
  m = fmaxf(fmaxf(red0[0][cl], red0[1][cl]), fmaxf(red0[2][cl], red0[3][cl]));

  float s = 0.f;
  #pragma unroll
  for (int tj = 0; tj < 16; ++tj)
    #pragma unroll
    for (int r = 0; r < 4; ++r) {
      float e = __expf(sc[tj][r] - m);
      sc[tj][r] = e;
      s += e;
    }
  s += __shfl_xor(s, 16);
  s += __shfl_xor(s, 32);
  if (lane < 16) red1[wv][lane] = s;
  lds_barrier();
  const float sm0 = red1[0][cl] + red1[1][cl] + red1[2][cl] + red1[3][cl];
  const float iv0 = 1.f / sm0;

  // ---- out2 = e0*iv0 via LDS transpose chunks (256 j x 16 i), full-line stores ----
  float* stage = (float*)arena;                    // [256][17] f32
  const size_t o2base = ((size_t)(b * HEADS + h) * N_TOK + i0) * N_TOK;
  #pragma unroll
  for (int c = 0; c < 4; ++c) {
    #pragma unroll
    for (int tjl = 0; tjl < 4; ++tjl)
      #pragma unroll
      for (int r = 0; r < 4; ++r)
        stage[(tjl * 64 + wv * 16 + rg * 4 + r) * 17 + cl] = sc[c * 4 + tjl][r] * iv0;
    lds_barrier();
    #pragma unroll
    for (int k = 0; k < 4; ++k) {
      int row = wv * 4 + k;
      #pragma unroll
      for (int e = 0; e < 4; ++e) {
        float v = stage[(e * 64 + lane) * 17 + row];
        out2[o2base + (size_t)row * N_TOK + c * 256 + e * 64 + lane] = v;
      }
    }
    lds_barrier();
  }

  // ---- P = e0 * exp(bias) / sum1 ----
  const int i_row = i0 + cl;
  const int ri = i_row >> 5, ci = i_row & 31;
  const int jbase = wv * 16 + rg * 4;
  float iv1;
  if (rpe_p[0]) {
    const float* bt = bias2e + h;
    float s1 = 0.f;
    #pragma unroll
    for (int tj = 0; tj < 16; ++tj)
      #pragma unroll
      for (int r = 0; r < 4; ++r) {
        int j = tj * 64 + jbase + r;
        int dr = ri - (j >> 5), dc = ci - (j & 31);
        int idx = dr * 63 + dc + 1984;
        float v = sc[tj][r] * bt[idx * 8];
        sc[tj][r] = v;
        s1 += v;
      }
    s1 += __shfl_xor(s1, 16);
    s1 += __shfl_xor(s1, 32);
    if (lane < 16) red0[wv][lane] = s1;
    lds_barrier();
    iv1 = 1.f / (red0[0][cl] + red0[1][cl] + red0[2][cl] + red0[3][cl]);
  } else {
    iv1 = iv0;
  }

  // ---- pack P^T to wave-private LDS: P_lds[i=cl][wv*256 + tj*16 + rg*4 + r] bf16 ----
  // wave-private (own columns) -> no barrier needed before PV reads (lgkmcnt only)
  unsigned short* P_lds = (unsigned short*)arena;  // [16][1032]
  #pragma unroll
  for (int tj = 0; tj < 16; ++tj) {
    unsigned u0 = pack2bf(sc[tj][0] * iv1, sc[tj][1] * iv1);
    unsigned u1 = pack2bf(sc[tj][2] * iv1, sc[tj][3] * iv1);
    uint2 uu; uu.x = u0; uu.y = u1;
    *(uint2*)&P_lds[cl * 1032 + wv * 256 + tj * 16 + rg * 4] = uu;
  }

  // ---- PV (swapped): O^T = mfma(Vt-frag, P^T-frag); partial over wave's 256 j ----
  const size_t vtb = (size_t)bh * 64;
  f32x4 oacc[4];
  #pragma unroll
  for (int dt = 0; dt < 4; ++dt) oacc[dt] = (f32x4){0.f, 0.f, 0.f, 0.f};
  const int vcol = (rg >> 1) * 64 + wv * 16 + (rg & 1) * 8;
  #pragma unroll
  for (int w = 0; w < 8; ++w) {
    bf16x8 pb = *(const bf16x8*)&P_lds[cl * 1032 + wv * 256 + (2 * w + (rg >> 1)) * 16 + (rg & 1) * 8];
    #pragma unroll
    for (int dt = 0; dt < 4; ++dt) {
      bf16x8 va = *(const bf16x8*)&Vt[(vtb + dt * 16 + cl) * N_TOK + w * 128 + vcol];
      oacc[dt] = MFMA16(va, pb, oacc[dt], 0, 0, 0);
    }
  }

  // ---- cross-wave O reduction: buf[wv][i][d] ----
  lds_barrier();                                    // all P_lds reads done before overwrite
  float* buf = (float*)arena;                       // [4][16][65] (pitch 1040 f32/wave)
  #pragma unroll
  for (int dt = 0; dt < 4; ++dt)
    #pragma unroll
    for (int r = 0; r < 4; ++r)
      buf[wv * 1040 + cl * 65 + dt * 16 + rg * 4 + r] = oacc[dt][r];
  lds_barrier();

  const int i_ = t >> 4, dq = t & 15;
  float o[4];
  #pragma unroll
  for (int k = 0; k < 4; ++k) {
    int d = dq * 4 + k;
    o[k] = buf[0 * 1040 + i_ * 65 + d] + buf[1 * 1040 + i_ * 65 + d]
         + buf[2 * 1040 + i_ * 65 + d] + buf[3 * 1040 + i_ * 65 + d];
  }
  short4 os;
  os.x = f2bf(o[0]); os.y = f2bf(o[1]); os.z = f2bf(o[2]); os.w = f2bf(o[3]);
  *(short4*)&Obuf[(rowbase + i0 + i_) * INNER + h * DIM_HEAD + dq * 4] = os;
}

extern "C" void kernel_launch(void* const* d_in, const int* in_sizes, int n_in,
                              void* d_out, int out_size, void* d_ws, size_t ws_size,
                              hipStream_t stream) {
  const float* x    = (const float*)d_in[0];
  const float* Wqkv = (const float*)d_in[1];
  const float* Wout = (const float*)d_in[2];
  const float* bout = (const float*)d_in[3];
  const float* rel  = (const float*)d_in[4];
  const float* sita = (const float*)d_in[5];
  const int*   rpe  = (const int*)d_in[6];

  char* ws = (char*)d_ws;
  short* xb     = (short*)(ws);                 //  8 MB  x bf16 (dead after gemm1)
  short* WqT    = (short*)(ws + 8388608);       //  1.5MB W_qkv^T (dead after gemm1)
  short* WoT    = (short*)(ws + 9961472);       //  0.5MB W_out^T
  short* qkv    = (short*)(ws + 10485760);      // 24 MB  qkv bf16 [8192][1536]
  short* Obuf   = (short*)(ws + 35651584);      //  8 MB  attn-out bf16 [8192][512]
  short* Vt     = (short*)(ws);                 //  8 MB  V^T [64][64][1024] (reuses xb)
  float* bias2e = (float*)(ws + 8388608);       // 127 KB exp'd fused bias (reuses WqT)

  float* out1 = (float*)d_out;
  float* out2 = out1 + (size_t)BATCH * N_TOK * DIMM;

  hipLaunchKernelGGL(cvt_bf16_kernel, dim3(4096), dim3(256), 0, stream,
                     x, xb, BATCH * N_TOK * DIMM);
  hipLaunchKernelGGL(tr_cvt_kernel, dim3((512 * 1536 + 255) / 256), dim3(256), 0, stream,
                     Wqkv, WqT, 512, 1536);
  hipLaunchKernelGGL(tr_cvt_kernel, dim3((512 * 512 + 255) / 256), dim3(256), 0, stream,
                     Wout, WoT, 512, 512);
  hipLaunchKernelGGL((gemm_kernel<1, 0>), dim3(12, 64), dim3(256), 0, stream,
                     xb, WqT, (void*)qkv, (const float*)nullptr, 8192, 1536, 512);
  // xb / WqT regions are dead now -> Vt / bias2e may overwrite them
  hipLaunchKernelGGL(bias2e_kernel, dim3((3969 * HEADS + 255) / 256), dim3(256), 0, stream,
                     rel, sita, bias2e);
  hipLaunchKernelGGL(v_tr_kernel, dim3(16, 64), dim3(256), 0, stream, qkv, Vt);
  hipLaunchKernelGGL(attn_kernel, dim3(4096), dim3(256), 0, stream,
                     qkv, Vt, bias2e, rpe, out2, Obuf);
  hipLaunchKernelGGL((gemm_kernel<0, 1>), dim3(4, 64), dim3(256), 0, stream,
                     Obuf, WoT, d_out, bout, 8192, 512, 512);
}

// Round 9
// 270.480 us; speedup vs baseline: 2.2303x; 1.3434x over previous
//
#include <hip/hip_runtime.h>
#include <hip/hip_bf16.h>

typedef __attribute__((ext_vector_type(8))) short bf16x8;
typedef __attribute__((ext_vector_type(4))) float f32x4;
typedef __attribute__((ext_vector_type(4))) unsigned int uint32x4;

#define N_TOK 1024
#define HEADS 8
#define DIM_HEAD 64
#define BATCH 8
#define DIMM 512
#define INNER 512
#define QKV_COLS 1536

#define MFMA16 __builtin_amdgcn_mfma_f32_16x16x32_bf16

__device__ inline short f2bf(float f) {
  union { float f; unsigned u; } v;
  v.f = f;
  unsigned r = v.u + 0x7fffu + ((v.u >> 16) & 1u);  // RNE
  return (short)(r >> 16);
}

__device__ inline unsigned pack2bf(float a, float b) {
  return ((unsigned)(unsigned short)f2bf(a)) | (((unsigned)(unsigned short)f2bf(b)) << 16);
}

// LDS-only barrier: orders LDS across waves WITHOUT draining global stores
// (__syncthreads emits s_waitcnt vmcnt(0) which stalls on the HBM write stream).
__device__ inline void lds_barrier() {
  asm volatile("s_waitcnt lgkmcnt(0)" ::: "memory");
  __builtin_amdgcn_s_barrier();
  asm volatile("" ::: "memory");
}

// ---------------- elementwise fp32 -> bf16 ----------------
__global__ void cvt_bf16_kernel(const float* __restrict__ in, short* __restrict__ out, int n) {
  int i = (blockIdx.x * 256 + threadIdx.x) * 4;
  if (i >= n) return;
  float4 v = *(const float4*)&in[i];
  short4 o;
  o.x = f2bf(v.x); o.y = f2bf(v.y); o.z = f2bf(v.z); o.w = f2bf(v.w);
  *(short4*)&out[i] = o;
}

// ---------------- transpose + convert: W[K][Nc] -> Wt[Nc][K] bf16 ----------------
__global__ void tr_cvt_kernel(const float* __restrict__ W, short* __restrict__ Wt, int K, int Nc) {
  int id = blockIdx.x * 256 + threadIdx.x;
  if (id >= K * Nc) return;
  int n = id % Nc, k = id / Nc;
  Wt[n * K + k] = f2bf(W[id]);
}

// ------- fused EXP bias table, TRANSPOSED [h][4096]:
// bias2e[h*4096+idx] = exp(rel[idx][h] + 0.01*exp(-factor_h*dis(idx)))
// (h-major layout: a wave's 28-consecutive-idx gather spans ~112B = 2-3 cache-line
//  segments instead of ~900B/14-28 segments with the old [idx][8] layout -> ~14x less
//  TA address-processing, which R8 analysis identified as the serialized resource.)
__global__ void bias2e_kernel(const float* __restrict__ rel, const float* __restrict__ headsita,
                              float* __restrict__ bias2e) {
  int e = blockIdx.x * 256 + threadIdx.x;
  if (e >= HEADS * 4096) return;
  int h = e >> 12, idx = e & 4095;
  if (idx >= 3969) return;
  int dr = idx / 63 - 31;
  int dc = idx % 63 - 31;
  float th = headsita[h];
  float factor = 1.f / (2.f * th * th + 1e-10f);
  float dis = (float)(dr * dr + dc * dc) * (1.0f / 1024.0f);
  bias2e[e] = __expf(rel[idx * HEADS + h] + 0.01f * __expf(-factor * dis));
}

// ---------------- V transpose: qkv V-slice -> Vt[bh][64 d][1024 j] ----------------
__global__ __launch_bounds__(256)
void v_tr_kernel(const short* __restrict__ qkv, short* __restrict__ Vt) {
  __shared__ short T[64][72];
  int t = threadIdx.x;
  int j0 = blockIdx.x * 64;
  int bh = blockIdx.y;
  int b = bh >> 3, h = bh & 7;
  #pragma unroll
  for (int c = 0; c < 2; ++c) {
    int idn = c * 256 + t;
    int j = idn >> 3, dc = (idn & 7) * 8;
    *(int4*)&T[j][dc] =
      *(const int4*)&qkv[(size_t)(b * N_TOK + j0 + j) * QKV_COLS + 2 * INNER + h * DIM_HEAD + dc];
  }
  lds_barrier();
  #pragma unroll
  for (int c = 0; c < 2; ++c) {
    int idn = c * 256 + t;
    int d = idn >> 3, je = (idn & 7) * 8;
    short tmp[8];
    #pragma unroll
    for (int e = 0; e < 8; ++e) tmp[e] = T[je + e][d];
    *(int4*)&Vt[((size_t)bh * 64 + d) * N_TOK + j0 + je] = *(int4*)tmp;
  }
}

// ---------------- bf16 MFMA GEMM with register prefetch + LDS-only barriers ----------------
template<int OUT_BF16, int ADD_BIAS>
__global__ __launch_bounds__(256)
void gemm_kernel(const short* __restrict__ A, const short* __restrict__ Bt,
                 void* __restrict__ C, const float* __restrict__ bias,
                 int M, int Nc, int K)
{
  __shared__ short Ash[128][40];
  __shared__ short Bsh[128][40];
  const int t = threadIdx.x;
  const int lane = t & 63, wave = t >> 6;
  const int wm = wave >> 1, wn = wave & 1;
  const int m0 = blockIdx.y * 128, n0 = blockIdx.x * 128;
  f32x4 acc[4][4] = {};
  int4 sa[2], sb[2];
  #pragma unroll
  for (int c = 0; c < 2; ++c) {
    int id = c * 256 + t, row = id >> 2, kc = (id & 3) * 8;
    sa[c] = *(const int4*)&A[(size_t)(m0 + row) * K + kc];
    sb[c] = *(const int4*)&Bt[(size_t)(n0 + row) * K + kc];
  }
  for (int k0 = 0; k0 < K; k0 += 32) {
    lds_barrier();
    #pragma unroll
    for (int c = 0; c < 2; ++c) {
      int id = c * 256 + t, row = id >> 2, kc = (id & 3) * 8;
      *(int4*)&Ash[row][kc] = sa[c];
      *(int4*)&Bsh[row][kc] = sb[c];
    }
    lds_barrier();
    if (k0 + 32 < K) {
      #pragma unroll
      for (int c = 0; c < 2; ++c) {
        int id = c * 256 + t, row = id >> 2, kc = (id & 3) * 8;
        sa[c] = *(const int4*)&A[(size_t)(m0 + row) * K + k0 + 32 + kc];
        sb[c] = *(const int4*)&Bt[(size_t)(n0 + row) * K + k0 + 32 + kc];
      }
    }
    bf16x8 af[4], bfr[4];
    #pragma unroll
    for (int m = 0; m < 4; ++m)
      af[m] = *(const bf16x8*)&Ash[wm*64 + m*16 + (lane & 15)][(lane >> 4) * 8];
    #pragma unroll
    for (int n = 0; n < 4; ++n)
      bfr[n] = *(const bf16x8*)&Bsh[wn*64 + n*16 + (lane & 15)][(lane >> 4) * 8];
    #pragma unroll
    for (int m = 0; m < 4; ++m)
      #pragma unroll
      for (int n = 0; n < 4; ++n)
        acc[m][n] = MFMA16(af[m], bfr[n], acc[m][n], 0, 0, 0);
  }
  const int r0 = (lane >> 4) * 4, c0 = lane & 15;
  #pragma unroll
  for (int m = 0; m < 4; ++m)
    #pragma unroll
    for (int n = 0; n < 4; ++n) {
      int col = n0 + wn*64 + n*16 + c0;
      float bv = ADD_BIAS ? bias[col] : 0.f;
      #pragma unroll
      for (int r = 0; r < 4; ++r) {
        int row = m0 + wm*64 + m*16 + r0 + r;
        float v = acc[m][n][r] + bv;
        if (OUT_BF16) ((short*)C)[(size_t)row * Nc + col] = f2bf(v);
        else          ((float*)C)[(size_t)row * Nc + col] = v;
      }
    }
}

// ---------------- fused attention v9: R8 structure + [h][4096] bias table ----------------
// ONLY change vs R8 (253us): bias gather uses h-major table -> bt[idx] (4B stride)
// instead of bt[idx*8] (32B stride). Targets the TA address-processing bottleneck.
__global__ __launch_bounds__(256, 4)
void attn_kernel(const short* __restrict__ qkv,
                 const short* __restrict__ Vt,        // [bh][64][1024]
                 const float* __restrict__ bias2e,    // [8][4096] = exp(rel + 0.01*gauss)
                 const int* __restrict__ rpe_p,
                 float* __restrict__ out2,            // softmax(dots0) [B,H,N,N]
                 short* __restrict__ Obuf)            // [B*N][512] bf16
{
  __shared__ __align__(16) char arena[33024];  // time-shared: stage / P_lds / buf
  __shared__ float red0[4][16];
  __shared__ float red1[4][16];

  const int t = threadIdx.x;
  const int lane = t & 63, wv = t >> 6;
  const int rg = lane >> 4, cl = lane & 15;

  const int id = blockIdx.x;                 // XCD-swizzled (bijective): same-bh -> same XCD
  const int bh = (id & 7) * 8 + ((id >> 3) & 7);
  const int i0 = (id >> 6) * 16;
  const int b = bh >> 3, h = bh & 7;
  const size_t rowbase = (size_t)b * N_TOK;

  // ---- Q fragments (B-operand): Q[i0+cl][rg*8 / +32] ----
  const size_t qoff = (rowbase + i0 + cl) * QKV_COLS + h * DIM_HEAD;
  const bf16x8 qf0 = *(const bf16x8*)&qkv[qoff + rg * 8];
  const bf16x8 qf1 = *(const bf16x8*)&qkv[qoff + 32 + rg * 8];

  // ---- QK^T (swapped): sc[tj] rows j = tj*64 + wv*16 + rg*4 + r, col i = i0+cl ----
  const short* krow = qkv + (rowbase + wv * 16 + cl) * QKV_COLS + INNER + h * DIM_HEAD + rg * 8;
  const size_t KSTR = (size_t)64 * QKV_COLS;   // j-tile stride (shorts)
  f32x4 sc[16];
  bf16x8 a0 = *(const bf16x8*)&krow[0];
  bf16x8 a1 = *(const bf16x8*)&krow[32];
  #pragma unroll
  for (int tj = 0; tj < 16; ++tj) {
    bf16x8 n0, n1;
    if (tj < 15) {
      n0 = *(const bf16x8*)&krow[(tj + 1) * KSTR];
      n1 = *(const bf16x8*)&krow[(tj + 1) * KSTR + 32];
    }
    f32x4 z = (f32x4){0.f, 0.f, 0.f, 0.f};
    z = MFMA16(a0, qf0, z, 0, 0, 0);
    z = MFMA16(a1, qf1, z, 0, 0, 0);
    sc[tj] = z;
    a0 = n0; a1 = n1;
  }

  // ---- scale + softmax0 (per-lane scalar: row i = i0+cl fixed) ----
  float m = -1e30f;
  #pragma unroll
  for (int tj = 0; tj < 16; ++tj)
    #pragma unroll
    for (int r = 0; r < 4; ++r) {
      sc[tj][r] *= 0.125f;
      m = fmaxf(m, sc[tj][r]);
    }
  m = fmaxf(m, __shfl_xor(m, 16));
  m = fmaxf(m, __shfl_xor(m, 32));
  if (lane < 16) red0[wv][lane] = m;
  lds_barrier();
  m = fmaxf(fmaxf(red0[0][cl], red0[1][cl]), fmaxf(red0[2][cl], red0[3][cl]));

  float s = 0.f;
  #pragma unroll
  for (int tj = 0; tj < 16; ++tj)
    #pragma unroll
    for (int r = 0; r < 4; ++r) {
      float e = __expf(sc[tj][r] - m);
      sc[tj][r] = e;
      s += e;
    }
  s += __shfl_xor(s, 16);
  s += __shfl_xor(s, 32);
  if (lane < 16) red1[wv][lane] = s;
  lds_barrier();
  const float sm0 = red1[0][cl] + red1[1][cl] + red1[2][cl] + red1[3][cl];
  const float iv0 = 1.f / sm0;

  // ---- out2 = e0*iv0 via LDS transpose chunks (256 j x 16 i), full-line stores ----
  float* stage = (float*)arena;                    // [256][17] f32
  const size_t o2base = ((size_t)(b * HEADS + h) * N_TOK + i0) * N_TOK;
  #pragma unroll
  for (int c = 0; c < 4; ++c) {
    #pragma unroll
    for (int tjl = 0; tjl < 4; ++tjl)
      #pragma unroll
      for (int r = 0; r < 4; ++r)
        stage[(tjl * 64 + wv * 16 + rg * 4 + r) * 17 + cl] = sc[c * 4 + tjl][r] * iv0;
    lds_barrier();
    #pragma unroll
    for (int k = 0; k < 4; ++k) {
      int row = wv * 4 + k;
      #pragma unroll
      for (int e = 0; e < 4; ++e) {
        float v = stage[(e * 64 + lane) * 17 + row];
        out2[o2base + (size_t)row * N_TOK + c * 256 + e * 64 + lane] = v;
      }
    }
    lds_barrier();
  }

  // ---- P = e0 * exp(bias) / sum1 ----
  const int i_row = i0 + cl;
  const int ri = i_row >> 5, ci = i_row & 31;
  const int jbase = wv * 16 + rg * 4;
  float iv1;
  if (rpe_p[0]) {
    const float* bt = bias2e + (h << 12);        // [h][4096] h-major: 4B-stride gather
    float s1 = 0.f;
    #pragma unroll
    for (int tj = 0; tj < 16; ++tj)
      #pragma unroll
      for (int r = 0; r < 4; ++r) {
        int j = tj * 64 + jbase + r;
        int dr = ri - (j >> 5), dc = ci - (j & 31);
        int idx = dr * 63 + dc + 1984;
        float v = sc[tj][r] * bt[idx];
        sc[tj][r] = v;
        s1 += v;
      }
    s1 += __shfl_xor(s1, 16);
    s1 += __shfl_xor(s1, 32);
    if (lane < 16) red0[wv][lane] = s1;
    lds_barrier();
    iv1 = 1.f / (red0[0][cl] + red0[1][cl] + red0[2][cl] + red0[3][cl]);
  } else {
    iv1 = iv0;
  }

  // ---- pack P^T to wave-private LDS: P_lds[i=cl][wv*256 + tj*16 + rg*4 + r] bf16 ----
  // wave-private (own columns) -> no barrier needed before PV reads (lgkmcnt only)
  unsigned short* P_lds = (unsigned short*)arena;  // [16][1032]
  #pragma unroll
  for (int tj = 0; tj < 16; ++tj) {
    unsigned u0 = pack2bf(sc[tj][0] * iv1, sc[tj][1] * iv1);
    unsigned u1 = pack2bf(sc[tj][2] * iv1, sc[tj][3] * iv1);
    uint2 uu; uu.x = u0; uu.y = u1;
    *(uint2*)&P_lds[cl * 1032 + wv * 256 + tj * 16 + rg * 4] = uu;
  }

  // ---- PV (swapped): O^T = mfma(Vt-frag, P^T-frag); partial over wave's 256 j ----
  const size_t vtb = (size_t)bh * 64;
  f32x4 oacc[4];
  #pragma unroll
  for (int dt = 0; dt < 4; ++dt) oacc[dt] = (f32x4){0.f, 0.f, 0.f, 0.f};
  const int vcol = (rg >> 1) * 64 + wv * 16 + (rg & 1) * 8;
  #pragma unroll
  for (int w = 0; w < 8; ++w) {
    bf16x8 pb = *(const bf16x8*)&P_lds[cl * 1032 + wv * 256 + (2 * w + (rg >> 1)) * 16 + (rg & 1) * 8];
    #pragma unroll
    for (int dt = 0; dt < 4; ++dt) {
      bf16x8 va = *(const bf16x8*)&Vt[(vtb + dt * 16 + cl) * N_TOK + w * 128 + vcol];
      oacc[dt] = MFMA16(va, pb, oacc[dt], 0, 0, 0);
    }
  }

  // ---- cross-wave O reduction: buf[wv][i][d] ----
  lds_barrier();                                    // all P_lds reads done before overwrite
  float* buf = (float*)arena;                       // [4][16][65] (pitch 1040 f32/wave)
  #pragma unroll
  for (int dt = 0; dt < 4; ++dt)
    #pragma unroll
    for (int r = 0; r < 4; ++r)
      buf[wv * 1040 + cl * 65 + dt * 16 + rg * 4 + r] = oacc[dt][r];
  lds_barrier();

  const int i_ = t >> 4, dq = t & 15;
  float o[4];
  #pragma unroll
  for (int k = 0; k < 4; ++k) {
    int d = dq * 4 + k;
    o[k] = buf[0 * 1040 + i_ * 65 + d] + buf[1 * 1040 + i_ * 65 + d]
         + buf[2 * 1040 + i_ * 65 + d] + buf[3 * 1040 + i_ * 65 + d];
  }
  short4 os;
  os.x = f2bf(o[0]); os.y = f2bf(o[1]); os.z = f2bf(o[2]); os.w = f2bf(o[3]);
  *(short4*)&Obuf[(rowbase + i0 + i_) * INNER + h * DIM_HEAD + dq * 4] = os;
}

extern "C" void kernel_launch(void* const* d_in, const int* in_sizes, int n_in,
                              void* d_out, int out_size, void* d_ws, size_t ws_size,
                              hipStream_t stream) {
  const float* x    = (const float*)d_in[0];
  const float* Wqkv = (const float*)d_in[1];
  const float* Wout = (const float*)d_in[2];
  const float* bout = (const float*)d_in[3];
  const float* rel  = (const float*)d_in[4];
  const float* sita = (const float*)d_in[5];
  const int*   rpe  = (const int*)d_in[6];

  char* ws = (char*)d_ws;
  short* xb     = (short*)(ws);                 //  8 MB  x bf16 (dead after gemm1)
  short* WqT    = (short*)(ws + 8388608);       //  1.5MB W_qkv^T (dead after gemm1)
  short* WoT    = (short*)(ws + 9961472);       //  0.5MB W_out^T
  short* qkv    = (short*)(ws + 10485760);      // 24 MB  qkv bf16 [8192][1536]
  short* Obuf   = (short*)(ws + 35651584);      //  8 MB  attn-out bf16 [8192][512]
  short* Vt     = (short*)(ws);                 //  8 MB  V^T [64][64][1024] (reuses xb)
  float* bias2e = (float*)(ws + 8388608);       // 128 KB exp'd fused bias [8][4096] (reuses WqT)

  float* out1 = (float*)d_out;
  float* out2 = out1 + (size_t)BATCH * N_TOK * DIMM;

  hipLaunchKernelGGL(cvt_bf16_kernel, dim3(4096), dim3(256), 0, stream,
                     x, xb, BATCH * N_TOK * DIMM);
  hipLaunchKernelGGL(tr_cvt_kernel, dim3((512 * 1536 + 255) / 256), dim3(256), 0, stream,
                     Wqkv, WqT, 512, 1536);
  hipLaunchKernelGGL(tr_cvt_kernel, dim3((512 * 512 + 255) / 256), dim3(256), 0, stream,
                     Wout, WoT, 512, 512);
  hipLaunchKernelGGL((gemm_kernel<1, 0>), dim3(12, 64), dim3(256), 0, stream,
                     xb, WqT, (void*)qkv, (const float*)nullptr, 8192, 1536, 512);
  // xb / WqT regions are dead now -> Vt / bias2e may overwrite them
  hipLaunchKernelGGL(bias2e_kernel, dim3((HEADS * 4096 + 255) / 256), dim3(256), 0, stream,
                     rel, sita, bias2e);
  hipLaunchKernelGGL(v_tr_kernel, dim3(16, 64), dim3(256), 0, stream, qkv, Vt);
  hipLaunchKernelGGL(attn_kernel, dim3(4096), dim3(256), 0, stream,
                     qkv, Vt, bias2e, rpe, out2, Obuf);
  hipLaunchKernelGGL((gemm_kernel<0, 1>), dim3(4, 64), dim3(256), 0, stream,
                     Obuf, WoT, d_out, bout, 8192, 512, 512);
}

// Round 10
// 269.849 us; speedup vs baseline: 2.2355x; 1.0023x over previous
//
#include <hip/hip_runtime.h>
#include <hip/hip_bf16.h>

typedef __attribute__((ext_vector_type(8))) short bf16x8;
typedef __attribute__((ext_vector_type(4))) float f32x4;
typedef float f32x4u __attribute__((ext_vector_type(4), aligned(4)));  // dword-aligned vec4
typedef __attribute__((ext_vector_type(4))) unsigned int uint32x4;

#define N_TOK 1024
#define HEADS 8
#define DIM_HEAD 64
#define BATCH 8
#define DIMM 512
#define INNER 512
#define QKV_COLS 1536

#define MFMA16 __builtin_amdgcn_mfma_f32_16x16x32_bf16

__device__ inline short f2bf(float f) {
  union { float f; unsigned u; } v;
  v.f = f;
  unsigned r = v.u + 0x7fffu + ((v.u >> 16) & 1u);  // RNE
  return (short)(r >> 16);
}

__device__ inline unsigned pack2bf(float a, float b) {
  return ((unsigned)(unsigned short)f2bf(a)) | (((unsigned)(unsigned short)f2bf(b)) << 16);
}

// LDS-only barrier: orders LDS across waves WITHOUT draining global stores
__device__ inline void lds_barrier() {
  asm volatile("s_waitcnt lgkmcnt(0)" ::: "memory");
  __builtin_amdgcn_s_barrier();
  asm volatile("" ::: "memory");
}

// ---------------- elementwise fp32 -> bf16 ----------------
__global__ void cvt_bf16_kernel(const float* __restrict__ in, short* __restrict__ out, int n) {
  int i = (blockIdx.x * 256 + threadIdx.x) * 4;
  if (i >= n) return;
  float4 v = *(const float4*)&in[i];
  short4 o;
  o.x = f2bf(v.x); o.y = f2bf(v.y); o.z = f2bf(v.z); o.w = f2bf(v.w);
  *(short4*)&out[i] = o;
}

// ---------------- transpose + convert: W[K][Nc] -> Wt[Nc][K] bf16 ----------------
__global__ void tr_cvt_kernel(const float* __restrict__ W, short* __restrict__ Wt, int K, int Nc) {
  int id = blockIdx.x * 256 + threadIdx.x;
  if (id >= K * Nc) return;
  int n = id % Nc, k = id / Nc;
  Wt[n * K + k] = f2bf(W[id]);
}

// ------- fused EXP bias table, TRANSPOSED [h][4096] -------
__global__ void bias2e_kernel(const float* __restrict__ rel, const float* __restrict__ headsita,
                              float* __restrict__ bias2e) {
  int e = blockIdx.x * 256 + threadIdx.x;
  if (e >= HEADS * 4096) return;
  int h = e >> 12, idx = e & 4095;
  if (idx >= 3969) return;
  int dr = idx / 63 - 31;
  int dc = idx % 63 - 31;
  float th = headsita[h];
  float factor = 1.f / (2.f * th * th + 1e-10f);
  float dis = (float)(dr * dr + dc * dc) * (1.0f / 1024.0f);
  bias2e[e] = __expf(rel[idx * HEADS + h] + 0.01f * __expf(-factor * dis));
}

// ---------------- V transpose: qkv V-slice -> Vt[bh][64 d][1024 j] ----------------
__global__ __launch_bounds__(256)
void v_tr_kernel(const short* __restrict__ qkv, short* __restrict__ Vt) {
  __shared__ short T[64][72];
  int t = threadIdx.x;
  int j0 = blockIdx.x * 64;
  int bh = blockIdx.y;
  int b = bh >> 3, h = bh & 7;
  #pragma unroll
  for (int c = 0; c < 2; ++c) {
    int idn = c * 256 + t;
    int j = idn >> 3, dc = (idn & 7) * 8;
    *(int4*)&T[j][dc] =
      *(const int4*)&qkv[(size_t)(b * N_TOK + j0 + j) * QKV_COLS + 2 * INNER + h * DIM_HEAD + dc];
  }
  lds_barrier();
  #pragma unroll
  for (int c = 0; c < 2; ++c) {
    int idn = c * 256 + t;
    int d = idn >> 3, je = (idn & 7) * 8;
    short tmp[8];
    #pragma unroll
    for (int e = 0; e < 8; ++e) tmp[e] = T[je + e][d];
    *(int4*)&Vt[((size_t)bh * 64 + d) * N_TOK + j0 + je] = *(int4*)tmp;
  }
}

// ---------------- bf16 MFMA GEMM with register prefetch + LDS-only barriers ----------------
template<int OUT_BF16, int ADD_BIAS>
__global__ __launch_bounds__(256)
void gemm_kernel(const short* __restrict__ A, const short* __restrict__ Bt,
                 void* __restrict__ C, const float* __restrict__ bias,
                 int M, int Nc, int K)
{
  __shared__ short Ash[128][40];
  __shared__ short Bsh[128][40];
  const int t = threadIdx.x;
  const int lane = t & 63, wave = t >> 6;
  const int wm = wave >> 1, wn = wave & 1;
  const int m0 = blockIdx.y * 128, n0 = blockIdx.x * 128;
  f32x4 acc[4][4] = {};
  int4 sa[2], sb[2];
  #pragma unroll
  for (int c = 0; c < 2; ++c) {
    int id = c * 256 + t, row = id >> 2, kc = (id & 3) * 8;
    sa[c] = *(const int4*)&A[(size_t)(m0 + row) * K + kc];
    sb[c] = *(const int4*)&Bt[(size_t)(n0 + row) * K + kc];
  }
  for (int k0 = 0; k0 < K; k0 += 32) {
    lds_barrier();
    #pragma unroll
    for (int c = 0; c < 2; ++c) {
      int id = c * 256 + t, row = id >> 2, kc = (id & 3) * 8;
      *(int4*)&Ash[row][kc] = sa[c];
      *(int4*)&Bsh[row][kc] = sb[c];
    }
    lds_barrier();
    if (k0 + 32 < K) {
      #pragma unroll
      for (int c = 0; c < 2; ++c) {
        int id = c * 256 + t, row = id >> 2, kc = (id & 3) * 8;
        sa[c] = *(const int4*)&A[(size_t)(m0 + row) * K + k0 + 32 + kc];
        sb[c] = *(const int4*)&Bt[(size_t)(n0 + row) * K + k0 + 32 + kc];
      }
    }
    bf16x8 af[4], bfr[4];
    #pragma unroll
    for (int m = 0; m < 4; ++m)
      af[m] = *(const bf16x8*)&Ash[wm*64 + m*16 + (lane & 15)][(lane >> 4) * 8];
    #pragma unroll
    for (int n = 0; n < 4; ++n)
      bfr[n] = *(const bf16x8*)&Bsh[wn*64 + n*16 + (lane & 15)][(lane >> 4) * 8];
    #pragma unroll
    for (int m = 0; m < 4; ++m)
      #pragma unroll
      for (int n = 0; n < 4; ++n)
        acc[m][n] = MFMA16(af[m], bfr[n], acc[m][n], 0, 0, 0);
  }
  const int r0 = (lane >> 4) * 4, c0 = lane & 15;
  #pragma unroll
  for (int m = 0; m < 4; ++m)
    #pragma unroll
    for (int n = 0; n < 4; ++n) {
      int col = n0 + wn*64 + n*16 + c0;
      float bv = ADD_BIAS ? bias[col] : 0.f;
      #pragma unroll
      for (int r = 0; r < 4; ++r) {
        int row = m0 + wm*64 + m*16 + r0 + r;
        float v = acc[m][n][r] + bv;
        if (OUT_BF16) ((short*)C)[(size_t)row * Nc + col] = f2bf(v);
        else          ((float*)C)[(size_t)row * Nc + col] = v;
      }
    }
}

// ---------------- fused attention v10: R9 + vectorized bias (affine-idx dwordx4) ----------------
// idx(tj,r) = C - 126*tj - r (per-lane constant C) => one unaligned dwordx4 per tj
// replaces 64 scalar gathers + per-gather addr math. Scale folded into exp arg.
__global__ __launch_bounds__(256, 4)
void attn_kernel(const short* __restrict__ qkv,
                 const short* __restrict__ Vt,        // [bh][64][1024]
                 const float* __restrict__ bias2e,    // [8][4096] = exp(rel + 0.01*gauss)
                 const int* __restrict__ rpe_p,
                 float* __restrict__ out2,            // softmax(dots0) [B,H,N,N]
                 short* __restrict__ Obuf)            // [B*N][512] bf16
{
  __shared__ __align__(16) char arena[33024];  // time-shared: stage / P_lds / buf
  __shared__ float red0[4][16];
  __shared__ float red1[4][16];

  const int t = threadIdx.x;
  const int lane = t & 63, wv = t >> 6;
  const int rg = lane >> 4, cl = lane & 15;

  const int id = blockIdx.x;                 // XCD-swizzled (bijective): same-bh -> same XCD
  const int bh = (id & 7) * 8 + ((id >> 3) & 7);
  const int i0 = (id >> 6) * 16;
  const int b = bh >> 3, h = bh & 7;
  const size_t rowbase = (size_t)b * N_TOK;

  // ---- Q fragments (B-operand): Q[i0+cl][rg*8 / +32] ----
  const size_t qoff = (rowbase + i0 + cl) * QKV_COLS + h * DIM_HEAD;
  const bf16x8 qf0 = *(const bf16x8*)&qkv[qoff + rg * 8];
  const bf16x8 qf1 = *(const bf16x8*)&qkv[qoff + 32 + rg * 8];

  // ---- QK^T (swapped): sc[tj] rows j = tj*64 + wv*16 + rg*4 + r, col i = i0+cl ----
  const short* krow = qkv + (rowbase + wv * 16 + cl) * QKV_COLS + INNER + h * DIM_HEAD + rg * 8;
  const size_t KSTR = (size_t)64 * QKV_COLS;   // j-tile stride (shorts)
  f32x4 sc[16];
  bf16x8 a0 = *(const bf16x8*)&krow[0];
  bf16x8 a1 = *(const bf16x8*)&krow[32];
  #pragma unroll
  for (int tj = 0; tj < 16; ++tj) {
    bf16x8 n0, n1;
    if (tj < 15) {
      n0 = *(const bf16x8*)&krow[(tj + 1) * KSTR];
      n1 = *(const bf16x8*)&krow[(tj + 1) * KSTR + 32];
    }
    f32x4 z = (f32x4){0.f, 0.f, 0.f, 0.f};
    z = MFMA16(a0, qf0, z, 0, 0, 0);
    z = MFMA16(a1, qf1, z, 0, 0, 0);
    sc[tj] = z;
    a0 = n0; a1 = n1;
  }

  // ---- softmax0 on RAW scores (scale folded into exp arg; order-preserving) ----
  float m = -1e30f;
  #pragma unroll
  for (int tj = 0; tj < 16; ++tj)
    #pragma unroll
    for (int r = 0; r < 4; ++r) m = fmaxf(m, sc[tj][r]);
  m = fmaxf(m, __shfl_xor(m, 16));
  m = fmaxf(m, __shfl_xor(m, 32));
  if (lane < 16) red0[wv][lane] = m;
  lds_barrier();
  m = fmaxf(fmaxf(red0[0][cl], red0[1][cl]), fmaxf(red0[2][cl], red0[3][cl]));

  float s = 0.f;
  #pragma unroll
  for (int tj = 0; tj < 16; ++tj)
    #pragma unroll
    for (int r = 0; r < 4; ++r) {
      float e = __expf((sc[tj][r] - m) * 0.125f);
      sc[tj][r] = e;
      s += e;
    }
  s += __shfl_xor(s, 16);
  s += __shfl_xor(s, 32);
  if (lane < 16) red1[wv][lane] = s;
  lds_barrier();
  const float sm0 = red1[0][cl] + red1[1][cl] + red1[2][cl] + red1[3][cl];
  const float iv0 = 1.f / sm0;

  // ---- out2 = e0*iv0 via LDS transpose chunks (256 j x 16 i), full-line stores ----
  float* stage = (float*)arena;                    // [256][17] f32
  const size_t o2base = ((size_t)(b * HEADS + h) * N_TOK + i0) * N_TOK;
  #pragma unroll
  for (int c = 0; c < 4; ++c) {
    #pragma unroll
    for (int tjl = 0; tjl < 4; ++tjl)
      #pragma unroll
      for (int r = 0; r < 4; ++r)
        stage[(tjl * 64 + wv * 16 + rg * 4 + r) * 17 + cl] = sc[c * 4 + tjl][r] * iv0;
    lds_barrier();
    #pragma unroll
    for (int k = 0; k < 4; ++k) {
      int row = wv * 4 + k;
      #pragma unroll
      for (int e = 0; e < 4; ++e) {
        float v = stage[(e * 64 + lane) * 17 + row];
        out2[o2base + (size_t)row * N_TOK + c * 256 + e * 64 + lane] = v;
      }
    }
    lds_barrier();
  }

  // ---- P = e0 * exp(bias) / sum1  -- vectorized: idx(tj,r) = C - 126*tj - r ----
  const int i_row = i0 + cl;
  const int ri = i_row >> 5, ci = i_row & 31;
  float iv1;
  if (rpe_p[0]) {
    const float* bt = bias2e + (h << 12);        // [h][4096]
    const int C = (ri - (wv >> 1)) * 63 + ci - ((wv & 1) * 16 + rg * 4) + 1984;
    float s1 = 0.f;
    #pragma unroll
    for (int tj = 0; tj < 16; ++tj) {
      f32x4u bv = *(const f32x4u*)&bt[C - tj * 126 - 3];   // [r3, r2, r1, r0]
      float v0 = sc[tj][0] * bv[3];
      float v1 = sc[tj][1] * bv[2];
      float v2 = sc[tj][2] * bv[1];
      float v3 = sc[tj][3] * bv[0];
      sc[tj][0] = v0; sc[tj][1] = v1; sc[tj][2] = v2; sc[tj][3] = v3;
      s1 += (v0 + v1) + (v2 + v3);
    }
    s1 += __shfl_xor(s1, 16);
    s1 += __shfl_xor(s1, 32);
    if (lane < 16) red0[wv][lane] = s1;
    lds_barrier();
    iv1 = 1.f / (red0[0][cl] + red0[1][cl] + red0[2][cl] + red0[3][cl]);
  } else {
    iv1 = iv0;
  }

  // ---- pack P^T to wave-private LDS: P_lds[i=cl][wv*256 + tj*16 + rg*4 + r] bf16 ----
  unsigned short* P_lds = (unsigned short*)arena;  // [16][1032]
  #pragma unroll
  for (int tj = 0; tj < 16; ++tj) {
    unsigned u0 = pack2bf(sc[tj][0] * iv1, sc[tj][1] * iv1);
    unsigned u1 = pack2bf(sc[tj][2] * iv1, sc[tj][3] * iv1);
    uint2 uu; uu.x = u0; uu.y = u1;
    *(uint2*)&P_lds[cl * 1032 + wv * 256 + tj * 16 + rg * 4] = uu;
  }

  // ---- PV (swapped): O^T = mfma(Vt-frag, P^T-frag); partial over wave's 256 j ----
  const size_t vtb = (size_t)bh * 64;
  f32x4 oacc[4];
  #pragma unroll
  for (int dt = 0; dt < 4; ++dt) oacc[dt] = (f32x4){0.f, 0.f, 0.f, 0.f};
  const int vcol = (rg >> 1) * 64 + wv * 16 + (rg & 1) * 8;
  #pragma unroll
  for (int w = 0; w < 8; ++w) {
    bf16x8 pb = *(const bf16x8*)&P_lds[cl * 1032 + wv * 256 + (2 * w + (rg >> 1)) * 16 + (rg & 1) * 8];
    #pragma unroll
    for (int dt = 0; dt < 4; ++dt) {
      bf16x8 va = *(const bf16x8*)&Vt[(vtb + dt * 16 + cl) * N_TOK + w * 128 + vcol];
      oacc[dt] = MFMA16(va, pb, oacc[dt], 0, 0, 0);
    }
  }

  // ---- cross-wave O reduction: buf[wv][i][d] ----
  lds_barrier();                                    // all P_lds reads done before overwrite
  float* buf = (float*)arena;                       // [4][16][65] (pitch 1040 f32/wave)
  #pragma unroll
  for (int dt = 0; dt < 4; ++dt)
    #pragma unroll
    for (int r = 0; r < 4; ++r)
      buf[wv * 1040 + cl * 65 + dt * 16 + rg * 4 + r] = oacc[dt][r];
  lds_barrier();

  const int i_ = t >> 4, dq = t & 15;
  float o[4];
  #pragma unroll
  for (int k = 0; k < 4; ++k) {
    int d = dq * 4 + k;
    o[k] = buf[0 * 1040 + i_ * 65 + d] + buf[1 * 1040 + i_ * 65 + d]
         + buf[2 * 1040 + i_ * 65 + d] + buf[3 * 1040 + i_ * 65 + d];
  }
  short4 os;
  os.x = f2bf(o[0]); os.y = f2bf(o[1]); os.z = f2bf(o[2]); os.w = f2bf(o[3]);
  *(short4*)&Obuf[(rowbase + i0 + i_) * INNER + h * DIM_HEAD + dq * 4] = os;
}

extern "C" void kernel_launch(void* const* d_in, const int* in_sizes, int n_in,
                              void* d_out, int out_size, void* d_ws, size_t ws_size,
                              hipStream_t stream) {
  const float* x    = (const float*)d_in[0];
  const float* Wqkv = (const float*)d_in[1];
  const float* Wout = (const float*)d_in[2];
  const float* bout = (const float*)d_in[3];
  const float* rel  = (const float*)d_in[4];
  const float* sita = (const float*)d_in[5];
  const int*   rpe  = (const int*)d_in[6];

  char* ws = (char*)d_ws;
  short* xb     = (short*)(ws);                 //  8 MB  x bf16 (dead after gemm1)
  short* WqT    = (short*)(ws + 8388608);       //  1.5MB W_qkv^T (dead after gemm1)
  short* WoT    = (short*)(ws + 9961472);       //  0.5MB W_out^T
  short* qkv    = (short*)(ws + 10485760);      // 24 MB  qkv bf16 [8192][1536]
  short* Obuf   = (short*)(ws + 35651584);      //  8 MB  attn-out bf16 [8192][512]
  short* Vt     = (short*)(ws);                 //  8 MB  V^T [64][64][1024] (reuses xb)
  float* bias2e = (float*)(ws + 8388608);       // 128 KB exp'd fused bias [8][4096] (reuses WqT)

  float* out1 = (float*)d_out;
  float* out2 = out1 + (size_t)BATCH * N_TOK * DIMM;

  hipLaunchKernelGGL(cvt_bf16_kernel, dim3(4096), dim3(256), 0, stream,
                     x, xb, BATCH * N_TOK * DIMM);
  hipLaunchKernelGGL(tr_cvt_kernel, dim3((512 * 1536 + 255) / 256), dim3(256), 0, stream,
                     Wqkv, WqT, 512, 1536);
  hipLaunchKernelGGL(tr_cvt_kernel, dim3((512 * 512 + 255) / 256), dim3(256), 0, stream,
                     Wout, WoT, 512, 512);
  hipLaunchKernelGGL((gemm_kernel<1, 0>), dim3(12, 64), dim3(256), 0, stream,
                     xb, WqT, (void*)qkv, (const float*)nullptr, 8192, 1536, 512);
  // xb / WqT regions are dead now -> Vt / bias2e may overwrite them
  hipLaunchKernelGGL(bias2e_kernel, dim3((HEADS * 4096 + 255) / 256), dim3(256), 0, stream,
                     rel, sita, bias2e);
  hipLaunchKernelGGL(v_tr_kernel, dim3(16, 64), dim3(256), 0, stream, qkv, Vt);
  hipLaunchKernelGGL(attn_kernel, dim3(4096), dim3(256), 0, stream,
                     qkv, Vt, bias2e, rpe, out2, Obuf);
  hipLaunchKernelGGL((gemm_kernel<0, 1>), dim3(4, 64), dim3(256), 0, stream,
                     Obuf, WoT, d_out, bout, 8192, 512, 512);
}

// Round 11
// 207.092 us; speedup vs baseline: 2.9130x; 1.3030x over previous
//
#include <hip/hip_runtime.h>
#include <hip/hip_bf16.h>

typedef __attribute__((ext_vector_type(8))) short bf16x8;
typedef __attribute__((ext_vector_type(4))) float f32x4;
typedef float f32x4u __attribute__((ext_vector_type(4), aligned(4)));  // dword-aligned vec4
typedef __attribute__((ext_vector_type(4))) unsigned int uint32x4;

#define N_TOK 1024
#define HEADS 8
#define DIM_HEAD 64
#define BATCH 8
#define DIMM 512
#define INNER 512
#define QKV_COLS 1536

#define MFMA16 __builtin_amdgcn_mfma_f32_16x16x32_bf16

__device__ inline short f2bf(float f) {
  union { float f; unsigned u; } v;
  v.f = f;
  unsigned r = v.u + 0x7fffu + ((v.u >> 16) & 1u);  // RNE
  return (short)(r >> 16);
}

__device__ inline unsigned pack2bf(float a, float b) {
  return ((unsigned)(unsigned short)f2bf(a)) | (((unsigned)(unsigned short)f2bf(b)) << 16);
}

// LDS-only barrier: orders LDS across waves WITHOUT draining global stores
__device__ inline void lds_barrier() {
  asm volatile("s_waitcnt lgkmcnt(0)" ::: "memory");
  __builtin_amdgcn_s_barrier();
  asm volatile("" ::: "memory");
}

// ---------------- elementwise fp32 -> bf16 ----------------
__global__ void cvt_bf16_kernel(const float* __restrict__ in, short* __restrict__ out, int n) {
  int i = (blockIdx.x * 256 + threadIdx.x) * 4;
  if (i >= n) return;
  float4 v = *(const float4*)&in[i];
  short4 o;
  o.x = f2bf(v.x); o.y = f2bf(v.y); o.z = f2bf(v.z); o.w = f2bf(v.w);
  *(short4*)&out[i] = o;
}

// ---------------- transpose + convert: W[K][Nc] -> Wt[Nc][K] bf16 ----------------
__global__ void tr_cvt_kernel(const float* __restrict__ W, short* __restrict__ Wt, int K, int Nc) {
  int id = blockIdx.x * 256 + threadIdx.x;
  if (id >= K * Nc) return;
  int n = id % Nc, k = id / Nc;
  Wt[n * K + k] = f2bf(W[id]);
}

// ------- fused EXP bias table, TRANSPOSED [h][4096] -------
__global__ void bias2e_kernel(const float* __restrict__ rel, const float* __restrict__ headsita,
                              float* __restrict__ bias2e) {
  int e = blockIdx.x * 256 + threadIdx.x;
  if (e >= HEADS * 4096) return;
  int h = e >> 12, idx = e & 4095;
  if (idx >= 3969) return;
  int dr = idx / 63 - 31;
  int dc = idx % 63 - 31;
  float th = headsita[h];
  float factor = 1.f / (2.f * th * th + 1e-10f);
  float dis = (float)(dr * dr + dc * dc) * (1.0f / 1024.0f);
  bias2e[e] = __expf(rel[idx * HEADS + h] + 0.01f * __expf(-factor * dis));
}

// ---------------- K/V fragment pack ----------------
// Kfrag[((bh*16+tj)*8 + wv*2+f)*64 + l] (16B each): K[b][tj*64+wv*16+(l&15)][f*32+(l>>4)*8..+8]
// Vfrag[((bh*8+w)*16 + wv*4+dt)*64 + l] (16B each): V^T fragment — 8 consecutive j for fixed d:
//   j = w*128 + ((l>>4)>>1)*64 + wv*16 + ((l>>4)&1)*8 + e,  d = dt*16 + (l&15)
// Attn then reads each fragment as ONE coalesced 1KB wave load (lane l at base+l*16B)
// instead of a 64-segment scatter — kills the TA address-serialization (R9's mechanism).
__global__ __launch_bounds__(256)
void kv_pack_kernel(const short* __restrict__ qkv, short* __restrict__ Kfrag,
                    short* __restrict__ Vfrag) {
  __shared__ short T[128][72];
  const int t = threadIdx.x;
  const int tile = blockIdx.x;       // 0..15: K tj; 16..23: V w
  const int bh = blockIdx.y;
  const int b = bh >> 3, h = bh & 7;
  if (tile < 16) {
    #pragma unroll
    for (int c = 0; c < 2; ++c) {
      int idn = c * 256 + t, j = idn >> 3, dc = (idn & 7) * 8;
      *(int4*)&T[j][dc] =
        *(const int4*)&qkv[(size_t)(b * N_TOK + tile * 64 + j) * QKV_COLS + INNER + h * DIM_HEAD + dc];
    }
    lds_barrier();
    #pragma unroll
    for (int c = 0; c < 2; ++c) {
      int fi = c * 256 + t, cidx = fi >> 6, l = fi & 63;
      int wv = cidx >> 1, f = cidx & 1;
      int4 v = *(const int4*)&T[wv * 16 + (l & 15)][f * 32 + (l >> 4) * 8];
      *(int4*)&Kfrag[(((size_t)bh * 16 + tile) * 8 + cidx) * 512 + l * 8] = v;
    }
  } else {
    const int w = tile - 16;
    #pragma unroll
    for (int c = 0; c < 4; ++c) {
      int idn = c * 256 + t, j = idn >> 3, dc = (idn & 7) * 8;
      *(int4*)&T[j][dc] =
        *(const int4*)&qkv[(size_t)(b * N_TOK + w * 128 + j) * QKV_COLS + 2 * INNER + h * DIM_HEAD + dc];
    }
    lds_barrier();
    #pragma unroll
    for (int c = 0; c < 4; ++c) {
      int fi = c * 256 + t, cidx = fi >> 6, l = fi & 63;
      int wv = cidx >> 2, dt = cidx & 3;
      int rg = l >> 4, cl = l & 15;
      int jj = (rg >> 1) * 64 + wv * 16 + (rg & 1) * 8;
      int d = dt * 16 + cl;
      short tmp[8];
      #pragma unroll
      for (int e = 0; e < 8; ++e) tmp[e] = T[jj + e][d];
      *(int4*)&Vfrag[(((size_t)bh * 8 + w) * 16 + cidx) * 512 + l * 8] = *(int4*)tmp;
    }
  }
}

// ---------------- bf16 MFMA GEMM with register prefetch + LDS-only barriers ----------------
template<int OUT_BF16, int ADD_BIAS>
__global__ __launch_bounds__(256)
void gemm_kernel(const short* __restrict__ A, const short* __restrict__ Bt,
                 void* __restrict__ C, const float* __restrict__ bias,
                 int M, int Nc, int K, int lda)
{
  __shared__ short Ash[128][40];
  __shared__ short Bsh[128][40];
  const int t = threadIdx.x;
  const int lane = t & 63, wave = t >> 6;
  const int wm = wave >> 1, wn = wave & 1;
  const int m0 = blockIdx.y * 128, n0 = blockIdx.x * 128;
  f32x4 acc[4][4] = {};
  int4 sa[2], sb[2];
  #pragma unroll
  for (int c = 0; c < 2; ++c) {
    int id = c * 256 + t, row = id >> 2, kc = (id & 3) * 8;
    sa[c] = *(const int4*)&A[(size_t)(m0 + row) * lda + kc];
    sb[c] = *(const int4*)&Bt[(size_t)(n0 + row) * K + kc];
  }
  for (int k0 = 0; k0 < K; k0 += 32) {
    lds_barrier();
    #pragma unroll
    for (int c = 0; c < 2; ++c) {
      int id = c * 256 + t, row = id >> 2, kc = (id & 3) * 8;
      *(int4*)&Ash[row][kc] = sa[c];
      *(int4*)&Bsh[row][kc] = sb[c];
    }
    lds_barrier();
    if (k0 + 32 < K) {
      #pragma unroll
      for (int c = 0; c < 2; ++c) {
        int id = c * 256 + t, row = id >> 2, kc = (id & 3) * 8;
        sa[c] = *(const int4*)&A[(size_t)(m0 + row) * lda + k0 + 32 + kc];
        sb[c] = *(const int4*)&Bt[(size_t)(n0 + row) * K + k0 + 32 + kc];
      }
    }
    bf16x8 af[4], bfr[4];
    #pragma unroll
    for (int m = 0; m < 4; ++m)
      af[m] = *(const bf16x8*)&Ash[wm*64 + m*16 + (lane & 15)][(lane >> 4) * 8];
    #pragma unroll
    for (int n = 0; n < 4; ++n)
      bfr[n] = *(const bf16x8*)&Bsh[wn*64 + n*16 + (lane & 15)][(lane >> 4) * 8];
    #pragma unroll
    for (int m = 0; m < 4; ++m)
      #pragma unroll
      for (int n = 0; n < 4; ++n)
        acc[m][n] = MFMA16(af[m], bfr[n], acc[m][n], 0, 0, 0);
  }
  const int r0 = (lane >> 4) * 4, c0 = lane & 15;
  #pragma unroll
  for (int m = 0; m < 4; ++m)
    #pragma unroll
    for (int n = 0; n < 4; ++n) {
      int col = n0 + wn*64 + n*16 + c0;
      float bv = ADD_BIAS ? bias[col] : 0.f;
      #pragma unroll
      for (int r = 0; r < 4; ++r) {
        int row = m0 + wm*64 + m*16 + r0 + r;
        float v = acc[m][n][r] + bv;
        if (OUT_BF16) ((short*)C)[(size_t)row * Nc + col] = f2bf(v);
        else          ((float*)C)[(size_t)row * Nc + col] = v;
      }
    }
}

// ---------------- fused attention v11: fragment-packed K/V (coalesced 1KB wave loads) ----------------
// R10 structure; K/V fragments from Kfrag/Vfrag (lane-linear). O written in-place into
// qkv's Q-slice (race-free: block (b,h,i0) is sole reader+writer of its rows x head cols).
__global__ __launch_bounds__(256, 4)
void attn_kernel(short* qkv,                          // NOT restrict: O aliases Q-slice
                 const short* __restrict__ Kfrag,
                 const short* __restrict__ Vfrag,
                 const float* __restrict__ bias2e,    // [8][4096]
                 const int* __restrict__ rpe_p,
                 float* __restrict__ out2)            // softmax(dots0) [B,H,N,N]
{
  __shared__ __align__(16) char arena[33024];  // time-shared: stage / P_lds / buf
  __shared__ float red0[4][16];
  __shared__ float red1[4][16];

  const int t = threadIdx.x;
  const int lane = t & 63, wv = t >> 6;
  const int rg = lane >> 4, cl = lane & 15;

  const int id = blockIdx.x;                 // XCD-swizzled (bijective): same-bh -> same XCD
  const int bh = (id & 7) * 8 + ((id >> 3) & 7);
  const int i0 = (id >> 6) * 16;
  const int b = bh >> 3, h = bh & 7;
  const size_t rowbase = (size_t)b * N_TOK;

  // ---- Q fragments (B-operand): Q[i0+cl][rg*8 / +32] ----
  const size_t qoff = (rowbase + i0 + cl) * QKV_COLS + h * DIM_HEAD;
  const bf16x8 qf0 = *(const bf16x8*)&qkv[qoff + rg * 8];
  const bf16x8 qf1 = *(const bf16x8*)&qkv[qoff + 32 + rg * 8];

  // ---- QK^T (swapped): fragment loads are lane-linear (coalesced 1KB/wave-instr) ----
  const short* kf = Kfrag + (((size_t)bh * 16) * 8 + wv * 2) * 512 + lane * 8;
  f32x4 sc[16];
  bf16x8 a0 = *(const bf16x8*)&kf[0];
  bf16x8 a1 = *(const bf16x8*)&kf[512];
  #pragma unroll
  for (int tj = 0; tj < 16; ++tj) {
    bf16x8 n0, n1;
    if (tj < 15) {
      n0 = *(const bf16x8*)&kf[(tj + 1) * 4096];
      n1 = *(const bf16x8*)&kf[(tj + 1) * 4096 + 512];
    }
    f32x4 z = (f32x4){0.f, 0.f, 0.f, 0.f};
    z = MFMA16(a0, qf0, z, 0, 0, 0);
    z = MFMA16(a1, qf1, z, 0, 0, 0);
    sc[tj] = z;
    a0 = n0; a1 = n1;
  }

  // ---- softmax0 on RAW scores (scale folded into exp arg) ----
  float m = -1e30f;
  #pragma unroll
  for (int tj = 0; tj < 16; ++tj)
    #pragma unroll
    for (int r = 0; r < 4; ++r) m = fmaxf(m, sc[tj][r]);
  m = fmaxf(m, __shfl_xor(m, 16));
  m = fmaxf(m, __shfl_xor(m, 32));
  if (lane < 16) red0[wv][lane] = m;
  lds_barrier();
  m = fmaxf(fmaxf(red0[0][cl], red0[1][cl]), fmaxf(red0[2][cl], red0[3][cl]));

  float s = 0.f;
  #pragma unroll
  for (int tj = 0; tj < 16; ++tj)
    #pragma unroll
    for (int r = 0; r < 4; ++r) {
      float e = __expf((sc[tj][r] - m) * 0.125f);
      sc[tj][r] = e;
      s += e;
    }
  s += __shfl_xor(s, 16);
  s += __shfl_xor(s, 32);
  if (lane < 16) red1[wv][lane] = s;
  lds_barrier();
  const float sm0 = red1[0][cl] + red1[1][cl] + red1[2][cl] + red1[3][cl];
  const float iv0 = 1.f / sm0;

  // ---- out2 = e0*iv0 via LDS transpose chunks (256 j x 16 i), full-line stores ----
  float* stage = (float*)arena;                    // [256][17] f32
  const size_t o2base = ((size_t)(b * HEADS + h) * N_TOK + i0) * N_TOK;
  #pragma unroll
  for (int c = 0; c < 4; ++c) {
    #pragma unroll
    for (int tjl = 0; tjl < 4; ++tjl)
      #pragma unroll
      for (int r = 0; r < 4; ++r)
        stage[(tjl * 64 + wv * 16 + rg * 4 + r) * 17 + cl] = sc[c * 4 + tjl][r] * iv0;
    lds_barrier();
    #pragma unroll
    for (int k = 0; k < 4; ++k) {
      int row = wv * 4 + k;
      #pragma unroll
      for (int e = 0; e < 4; ++e) {
        float v = stage[(e * 64 + lane) * 17 + row];
        out2[o2base + (size_t)row * N_TOK + c * 256 + e * 64 + lane] = v;
      }
    }
    lds_barrier();
  }

  // ---- P = e0 * exp(bias) / sum1  -- vectorized: idx(tj,r) = C - 126*tj - r ----
  const int i_row = i0 + cl;
  const int ri = i_row >> 5, ci = i_row & 31;
  float iv1;
  if (rpe_p[0]) {
    const float* bt = bias2e + (h << 12);        // [h][4096]
    const int C = (ri - (wv >> 1)) * 63 + ci - ((wv & 1) * 16 + rg * 4) + 1984;
    float s1 = 0.f;
    #pragma unroll
    for (int tj = 0; tj < 16; ++tj) {
      f32x4u bv = *(const f32x4u*)&bt[C - tj * 126 - 3];   // [r3, r2, r1, r0]
      float v0 = sc[tj][0] * bv[3];
      float v1 = sc[tj][1] * bv[2];
      float v2 = sc[tj][2] * bv[1];
      float v3 = sc[tj][3] * bv[0];
      sc[tj][0] = v0; sc[tj][1] = v1; sc[tj][2] = v2; sc[tj][3] = v3;
      s1 += (v0 + v1) + (v2 + v3);
    }
    s1 += __shfl_xor(s1, 16);
    s1 += __shfl_xor(s1, 32);
    if (lane < 16) red0[wv][lane] = s1;
    lds_barrier();
    iv1 = 1.f / (red0[0][cl] + red0[1][cl] + red0[2][cl] + red0[3][cl]);
  } else {
    iv1 = iv0;
  }

  // ---- pack P^T to wave-private LDS: P_lds[i=cl][wv*256 + tj*16 + rg*4 + r] bf16 ----
  unsigned short* P_lds = (unsigned short*)arena;  // [16][1032]
  #pragma unroll
  for (int tj = 0; tj < 16; ++tj) {
    unsigned u0 = pack2bf(sc[tj][0] * iv1, sc[tj][1] * iv1);
    unsigned u1 = pack2bf(sc[tj][2] * iv1, sc[tj][3] * iv1);
    uint2 uu; uu.x = u0; uu.y = u1;
    *(uint2*)&P_lds[cl * 1032 + wv * 256 + tj * 16 + rg * 4] = uu;
  }

  // ---- PV (swapped): O^T = mfma(Vfrag, P^T-frag); fragment loads lane-linear ----
  const short* vf = Vfrag + (((size_t)bh * 8) * 16 + wv * 4) * 512 + lane * 8;
  f32x4 oacc[4];
  #pragma unroll
  for (int dt = 0; dt < 4; ++dt) oacc[dt] = (f32x4){0.f, 0.f, 0.f, 0.f};
  #pragma unroll
  for (int w = 0; w < 8; ++w) {
    bf16x8 pb = *(const bf16x8*)&P_lds[cl * 1032 + wv * 256 + (2 * w + (rg >> 1)) * 16 + (rg & 1) * 8];
    #pragma unroll
    for (int dt = 0; dt < 4; ++dt) {
      bf16x8 va = *(const bf16x8*)&vf[w * 8192 + dt * 512];
      oacc[dt] = MFMA16(va, pb, oacc[dt], 0, 0, 0);
    }
  }

  // ---- cross-wave O reduction: buf[wv][i][d] ----
  lds_barrier();                                    // all P_lds reads done before overwrite
  float* buf = (float*)arena;                       // [4][16][65] (pitch 1040 f32/wave)
  #pragma unroll
  for (int dt = 0; dt < 4; ++dt)
    #pragma unroll
    for (int r = 0; r < 4; ++r)
      buf[wv * 1040 + cl * 65 + dt * 16 + rg * 4 + r] = oacc[dt][r];
  lds_barrier();

  const int i_ = t >> 4, dq = t & 15;
  float o[4];
  #pragma unroll
  for (int k = 0; k < 4; ++k) {
    int d = dq * 4 + k;
    o[k] = buf[0 * 1040 + i_ * 65 + d] + buf[1 * 1040 + i_ * 65 + d]
         + buf[2 * 1040 + i_ * 65 + d] + buf[3 * 1040 + i_ * 65 + d];
  }
  short4 os;
  os.x = f2bf(o[0]); os.y = f2bf(o[1]); os.z = f2bf(o[2]); os.w = f2bf(o[3]);
  // O in-place into qkv Q-slice (this block's own rows x head cols; Q already consumed)
  *(short4*)&qkv[(rowbase + i0 + i_) * QKV_COLS + h * DIM_HEAD + dq * 4] = os;
}

extern "C" void kernel_launch(void* const* d_in, const int* in_sizes, int n_in,
                              void* d_out, int out_size, void* d_ws, size_t ws_size,
                              hipStream_t stream) {
  const float* x    = (const float*)d_in[0];
  const float* Wqkv = (const float*)d_in[1];
  const float* Wout = (const float*)d_in[2];
  const float* bout = (const float*)d_in[3];
  const float* rel  = (const float*)d_in[4];
  const float* sita = (const float*)d_in[5];
  const int*   rpe  = (const int*)d_in[6];

  char* ws = (char*)d_ws;
  short* xb     = (short*)(ws);                 //  8 MB  x bf16 (dead after gemm1)
  short* WqT    = (short*)(ws + 8388608);       //  1.5MB W_qkv^T (dead after gemm1)
  short* WoT    = (short*)(ws + 9961472);       //  0.5MB W_out^T
  short* qkv    = (short*)(ws + 10485760);      // 24 MB  qkv bf16 [8192][1536]; Q-slice becomes O
  short* Kfrag  = (short*)(ws);                 //  8 MB  K fragments (reuses xb)
  short* Vfrag  = (short*)(ws + 35651584);      //  8 MB  V fragments (was Obuf)
  float* bias2e = (float*)(ws + 8388608);       // 128 KB exp'd fused bias [8][4096] (reuses WqT)

  float* out1 = (float*)d_out;
  float* out2 = out1 + (size_t)BATCH * N_TOK * DIMM;

  hipLaunchKernelGGL(cvt_bf16_kernel, dim3(4096), dim3(256), 0, stream,
                     x, xb, BATCH * N_TOK * DIMM);
  hipLaunchKernelGGL(tr_cvt_kernel, dim3((512 * 1536 + 255) / 256), dim3(256), 0, stream,
                     Wqkv, WqT, 512, 1536);
  hipLaunchKernelGGL(tr_cvt_kernel, dim3((512 * 512 + 255) / 256), dim3(256), 0, stream,
                     Wout, WoT, 512, 512);
  hipLaunchKernelGGL((gemm_kernel<1, 0>), dim3(12, 64), dim3(256), 0, stream,
                     xb, WqT, (void*)qkv, (const float*)nullptr, 8192, 1536, 512, 512);
  // xb / WqT regions are dead now -> Kfrag / bias2e may overwrite them
  hipLaunchKernelGGL(bias2e_kernel, dim3((HEADS * 4096 + 255) / 256), dim3(256), 0, stream,
                     rel, sita, bias2e);
  hipLaunchKernelGGL(kv_pack_kernel, dim3(24, 64), dim3(256), 0, stream, qkv, Kfrag, Vfrag);
  hipLaunchKernelGGL(attn_kernel, dim3(4096), dim3(256), 0, stream,
                     qkv, Kfrag, Vfrag, bias2e, rpe, out2);
  hipLaunchKernelGGL((gemm_kernel<0, 1>), dim3(4, 64), dim3(256), 0, stream,
                     qkv, WoT, d_out, bout, 8192, 512, 512, 1536);
}

// Round 12
// 167.143 us; speedup vs baseline: 3.6092x; 1.2390x over previous
//
#include <hip/hip_runtime.h>
#include <hip/hip_bf16.h>

typedef __attribute__((ext_vector_type(8))) short bf16x8;
typedef __attribute__((ext_vector_type(4))) float f32x4;
typedef float f32x4u __attribute__((ext_vector_type(4), aligned(4)));  // dword-aligned vec4
typedef __attribute__((ext_vector_type(4))) unsigned int uint32x4;

#define N_TOK 1024
#define HEADS 8
#define DIM_HEAD 64
#define BATCH 8
#define DIMM 512
#define INNER 512
#define QKV_COLS 1536

#define MFMA16 __builtin_amdgcn_mfma_f32_16x16x32_bf16

__device__ inline short f2bf(float f) {
  union { float f; unsigned u; } v;
  v.f = f;
  unsigned r = v.u + 0x7fffu + ((v.u >> 16) & 1u);  // RNE
  return (short)(r >> 16);
}

__device__ inline unsigned pack2bf(float a, float b) {
  return ((unsigned)(unsigned short)f2bf(a)) | (((unsigned)(unsigned short)f2bf(b)) << 16);
}

// LDS-only barrier: orders LDS across waves WITHOUT draining global stores
__device__ inline void lds_barrier() {
  asm volatile("s_waitcnt lgkmcnt(0)" ::: "memory");
  __builtin_amdgcn_s_barrier();
  asm volatile("" ::: "memory");
}

// direct global->LDS 16B/lane (dest = wave-uniform base + lane*16)
__device__ inline void gload_lds16(const short* g, short* l) {
  __builtin_amdgcn_global_load_lds(
      (const __attribute__((address_space(1))) void*)g,
      (__attribute__((address_space(3))) void*)l, 16, 0, 0);
}

// ---------------- elementwise fp32 -> bf16 ----------------
__global__ void cvt_bf16_kernel(const float* __restrict__ in, short* __restrict__ out, int n) {
  int i = (blockIdx.x * 256 + threadIdx.x) * 4;
  if (i >= n) return;
  float4 v = *(const float4*)&in[i];
  short4 o;
  o.x = f2bf(v.x); o.y = f2bf(v.y); o.z = f2bf(v.z); o.w = f2bf(v.w);
  *(short4*)&out[i] = o;
}

// ---------------- transpose + convert: W[K][Nc] -> Wt[Nc][K] bf16 ----------------
__global__ void tr_cvt_kernel(const float* __restrict__ W, short* __restrict__ Wt, int K, int Nc) {
  int id = blockIdx.x * 256 + threadIdx.x;
  if (id >= K * Nc) return;
  int n = id % Nc, k = id / Nc;
  Wt[n * K + k] = f2bf(W[id]);
}

// ------- fused EXP bias table, TRANSPOSED [h][4096] -------
__global__ void bias2e_kernel(const float* __restrict__ rel, const float* __restrict__ headsita,
                              float* __restrict__ bias2e) {
  int e = blockIdx.x * 256 + threadIdx.x;
  if (e >= HEADS * 4096) return;
  int h = e >> 12, idx = e & 4095;
  if (idx >= 3969) return;
  int dr = idx / 63 - 31;
  int dc = idx % 63 - 31;
  float th = headsita[h];
  float factor = 1.f / (2.f * th * th + 1e-10f);
  float dis = (float)(dr * dr + dc * dc) * (1.0f / 1024.0f);
  bias2e[e] = __expf(rel[idx * HEADS + h] + 0.01f * __expf(-factor * dis));
}

// ---------------- K/V fragment pack (unchanged from R11) ----------------
__global__ __launch_bounds__(256)
void kv_pack_kernel(const short* __restrict__ qkv, short* __restrict__ Kfrag,
                    short* __restrict__ Vfrag) {
  __shared__ short T[128][72];
  const int t = threadIdx.x;
  const int tile = blockIdx.x;       // 0..15: K tj; 16..23: V w
  const int bh = blockIdx.y;
  const int b = bh >> 3, h = bh & 7;
  if (tile < 16) {
    #pragma unroll
    for (int c = 0; c < 2; ++c) {
      int idn = c * 256 + t, j = idn >> 3, dc = (idn & 7) * 8;
      *(int4*)&T[j][dc] =
        *(const int4*)&qkv[(size_t)(b * N_TOK + tile * 64 + j) * QKV_COLS + INNER + h * DIM_HEAD + dc];
    }
    lds_barrier();
    #pragma unroll
    for (int c = 0; c < 2; ++c) {
      int fi = c * 256 + t, cidx = fi >> 6, l = fi & 63;
      int wv = cidx >> 1, f = cidx & 1;
      int4 v = *(const int4*)&T[wv * 16 + (l & 15)][f * 32 + (l >> 4) * 8];
      *(int4*)&Kfrag[(((size_t)bh * 16 + tile) * 8 + cidx) * 512 + l * 8] = v;
    }
  } else {
    const int w = tile - 16;
    #pragma unroll
    for (int c = 0; c < 4; ++c) {
      int idn = c * 256 + t, j = idn >> 3, dc = (idn & 7) * 8;
      *(int4*)&T[j][dc] =
        *(const int4*)&qkv[(size_t)(b * N_TOK + w * 128 + j) * QKV_COLS + 2 * INNER + h * DIM_HEAD + dc];
    }
    lds_barrier();
    #pragma unroll
    for (int c = 0; c < 4; ++c) {
      int fi = c * 256 + t, cidx = fi >> 6, l = fi & 63;
      int wv = cidx >> 2, dt = cidx & 3;
      int rg = l >> 4, cl = l & 15;
      int jj = (rg >> 1) * 64 + wv * 16 + (rg & 1) * 8;
      int d = dt * 16 + cl;
      short tmp[8];
      #pragma unroll
      for (int e = 0; e < 8; ++e) tmp[e] = T[jj + e][d];
      *(int4*)&Vfrag[(((size_t)bh * 8 + w) * 16 + cidx) * 512 + l * 8] = *(int4*)tmp;
    }
  }
}

// ---------------- bf16 MFMA GEMM, m97-style: global_load_lds w16, linear LDS ----------------
template<int OUT_BF16, int ADD_BIAS>
__global__ __launch_bounds__(256)
void gemm_kernel(const short* __restrict__ A, const short* __restrict__ Bt,
                 void* __restrict__ C, const float* __restrict__ bias,
                 int M, int Nc, int K, int lda)
{
  __shared__ short Ash[128 * 32];   // linear: row-major [128][32] (no pad; gload_lds needs it)
  __shared__ short Bsh[128 * 32];
  const int t = threadIdx.x;
  const int lane = t & 63, wave = t >> 6;
  const int wm = wave >> 1, wn = wave & 1;
  const int m0 = blockIdx.y * 128, n0 = blockIdx.x * 128;
  const int grow = wave * 32 + (lane >> 2);   // LDS row this lane writes (+ i*16)
  const int gcol = (lane & 3) * 8;            // 16B column chunk
  f32x4 acc[4][4] = {};
  for (int k0 = 0; k0 < K; k0 += 32) {
    lds_barrier();                            // prior ds_reads complete before overwrite
    #pragma unroll
    for (int i = 0; i < 2; ++i) {
      gload_lds16(&A[(size_t)(m0 + grow + i * 16) * lda + k0 + gcol],
                  &Ash[(wave * 32 + i * 16) * 32]);
      gload_lds16(&Bt[(size_t)(n0 + grow + i * 16) * K + k0 + gcol],
                  &Bsh[(wave * 32 + i * 16) * 32]);
    }
    asm volatile("s_waitcnt vmcnt(0)" ::: "memory");
    __builtin_amdgcn_s_barrier();
    asm volatile("" ::: "memory");
    bf16x8 af[4], bfr[4];
    #pragma unroll
    for (int m = 0; m < 4; ++m)
      af[m] = *(const bf16x8*)&Ash[(wm * 64 + m * 16 + (lane & 15)) * 32 + (lane >> 4) * 8];
    #pragma unroll
    for (int n = 0; n < 4; ++n)
      bfr[n] = *(const bf16x8*)&Bsh[(wn * 64 + n * 16 + (lane & 15)) * 32 + (lane >> 4) * 8];
    #pragma unroll
    for (int m = 0; m < 4; ++m)
      #pragma unroll
      for (int n = 0; n < 4; ++n)
        acc[m][n] = MFMA16(af[m], bfr[n], acc[m][n], 0, 0, 0);
  }
  const int r0 = (lane >> 4) * 4, c0 = lane & 15;
  #pragma unroll
  for (int m = 0; m < 4; ++m)
    #pragma unroll
    for (int n = 0; n < 4; ++n) {
      int col = n0 + wn*64 + n*16 + c0;
      float bv = ADD_BIAS ? bias[col] : 0.f;
      #pragma unroll
      for (int r = 0; r < 4; ++r) {
        int row = m0 + wm*64 + m*16 + r0 + r;
        float v = acc[m][n][r] + bv;
        if (OUT_BF16) ((short*)C)[(size_t)row * Nc + col] = f2bf(v);
        else          ((float*)C)[(size_t)row * Nc + col] = v;
      }
    }
}

// ---------------- fused attention v12: R11 + chunked P (LDS 33.8 -> ~17.9 KB) ----------------
// P packed/consumed in two wave-private half-passes so the arena never exceeds the
// out2 stage footprint (17408 B) -> LDS-bound occupancy doubles to 8 blocks/CU.
__global__ __launch_bounds__(256, 4)
void attn_kernel(short* qkv,                          // NOT restrict: O aliases Q-slice
                 const short* __restrict__ Kfrag,
                 const short* __restrict__ Vfrag,
                 const float* __restrict__ bias2e,    // [8][4096]
                 const int* __restrict__ rpe_p,
                 float* __restrict__ out2)            // softmax(dots0) [B,H,N,N]
{
  __shared__ __align__(16) char arena[17408];  // stage[256*17]f32 | P_c[16][520]bf16 | buf
  __shared__ float red0[4][16];
  __shared__ float red1[4][16];

  const int t = threadIdx.x;
  const int lane = t & 63, wv = t >> 6;
  const int rg = lane >> 4, cl = lane & 15;

  const int id = blockIdx.x;                 // XCD-swizzled (bijective): same-bh -> same XCD
  const int bh = (id & 7) * 8 + ((id >> 3) & 7);
  const int i0 = (id >> 6) * 16;
  const int b = bh >> 3, h = bh & 7;
  const size_t rowbase = (size_t)b * N_TOK;

  // ---- Q fragments (B-operand): Q[i0+cl][rg*8 / +32] ----
  const size_t qoff = (rowbase + i0 + cl) * QKV_COLS + h * DIM_HEAD;
  const bf16x8 qf0 = *(const bf16x8*)&qkv[qoff + rg * 8];
  const bf16x8 qf1 = *(const bf16x8*)&qkv[qoff + 32 + rg * 8];

  // ---- QK^T (swapped): fragment loads are lane-linear (coalesced 1KB/wave-instr) ----
  const short* kf = Kfrag + (((size_t)bh * 16) * 8 + wv * 2) * 512 + lane * 8;
  f32x4 sc[16];
  bf16x8 a0 = *(const bf16x8*)&kf[0];
  bf16x8 a1 = *(const bf16x8*)&kf[512];
  #pragma unroll
  for (int tj = 0; tj < 16; ++tj) {
    bf16x8 n0, n1;
    if (tj < 15) {
      n0 = *(const bf16x8*)&kf[(tj + 1) * 4096];
      n1 = *(const bf16x8*)&kf[(tj + 1) * 4096 + 512];
    }
    f32x4 z = (f32x4){0.f, 0.f, 0.f, 0.f};
    z = MFMA16(a0, qf0, z, 0, 0, 0);
    z = MFMA16(a1, qf1, z, 0, 0, 0);
    sc[tj] = z;
    a0 = n0; a1 = n1;
  }

  // ---- softmax0 on RAW scores (scale folded into exp arg) ----
  float m = -1e30f;
  #pragma unroll
  for (int tj = 0; tj < 16; ++tj)
    #pragma unroll
    for (int r = 0; r < 4; ++r) m = fmaxf(m, sc[tj][r]);
  m = fmaxf(m, __shfl_xor(m, 16));
  m = fmaxf(m, __shfl_xor(m, 32));
  if (lane < 16) red0[wv][lane] = m;
  lds_barrier();
  m = fmaxf(fmaxf(red0[0][cl], red0[1][cl]), fmaxf(red0[2][cl], red0[3][cl]));

  float s = 0.f;
  #pragma unroll
  for (int tj = 0; tj < 16; ++tj)
    #pragma unroll
    for (int r = 0; r < 4; ++r) {
      float e = __expf((sc[tj][r] - m) * 0.125f);
      sc[tj][r] = e;
      s += e;
    }
  s += __shfl_xor(s, 16);
  s += __shfl_xor(s, 32);
  if (lane < 16) red1[wv][lane] = s;
  lds_barrier();
  const float sm0 = red1[0][cl] + red1[1][cl] + red1[2][cl] + red1[3][cl];
  const float iv0 = 1.f / sm0;

  // ---- out2 = e0*iv0 via LDS transpose chunks (256 j x 16 i), full-line stores ----
  float* stage = (float*)arena;                    // [256][17] f32
  const size_t o2base = ((size_t)(b * HEADS + h) * N_TOK + i0) * N_TOK;
  #pragma unroll
  for (int c = 0; c < 4; ++c) {
    #pragma unroll
    for (int tjl = 0; tjl < 4; ++tjl)
      #pragma unroll
      for (int r = 0; r < 4; ++r)
        stage[(tjl * 64 + wv * 16 + rg * 4 + r) * 17 + cl] = sc[c * 4 + tjl][r] * iv0;
    lds_barrier();
    #pragma unroll
    for (int k = 0; k < 4; ++k) {
      int row = wv * 4 + k;
      #pragma unroll
      for (int e = 0; e < 4; ++e) {
        float v = stage[(e * 64 + lane) * 17 + row];
        out2[o2base + (size_t)row * N_TOK + c * 256 + e * 64 + lane] = v;
      }
    }
    lds_barrier();
  }

  // ---- P = e0 * exp(bias) / sum1  -- vectorized: idx(tj,r) = C - 126*tj - r ----
  const int i_row = i0 + cl;
  const int ri = i_row >> 5, ci = i_row & 31;
  float iv1;
  if (rpe_p[0]) {
    const float* bt = bias2e + (h << 12);        // [h][4096]
    const int C = (ri - (wv >> 1)) * 63 + ci - ((wv & 1) * 16 + rg * 4) + 1984;
    float s1 = 0.f;
    #pragma unroll
    for (int tj = 0; tj < 16; ++tj) {
      f32x4u bv = *(const f32x4u*)&bt[C - tj * 126 - 3];   // [r3, r2, r1, r0]
      float v0 = sc[tj][0] * bv[3];
      float v1 = sc[tj][1] * bv[2];
      float v2 = sc[tj][2] * bv[1];
      float v3 = sc[tj][3] * bv[0];
      sc[tj][0] = v0; sc[tj][1] = v1; sc[tj][2] = v2; sc[tj][3] = v3;
      s1 += (v0 + v1) + (v2 + v3);
    }
    s1 += __shfl_xor(s1, 16);
    s1 += __shfl_xor(s1, 32);
    if (lane < 16) red0[wv][lane] = s1;
    lds_barrier();
    iv1 = 1.f / (red0[0][cl] + red0[1][cl] + red0[2][cl] + red0[3][cl]);
  } else {
    iv1 = iv0;
  }

  // ---- chunked P pack + PV: two wave-private half-passes (no barriers needed;
  //      per-wave LDS ops are in-order, region is wave's own columns) ----
  unsigned short* P_c = (unsigned short*)arena;    // [16 i][4 wv x 130] pitch 520
  const short* vf = Vfrag + (((size_t)bh * 8) * 16 + wv * 4) * 512 + lane * 8;
  f32x4 oacc[4];
  #pragma unroll
  for (int dt = 0; dt < 4; ++dt) oacc[dt] = (f32x4){0.f, 0.f, 0.f, 0.f};
  #pragma unroll
  for (int ch = 0; ch < 2; ++ch) {
    #pragma unroll
    for (int tj8 = 0; tj8 < 8; ++tj8) {
      int tj = ch * 8 + tj8;
      unsigned u0 = pack2bf(sc[tj][0] * iv1, sc[tj][1] * iv1);
      unsigned u1 = pack2bf(sc[tj][2] * iv1, sc[tj][3] * iv1);
      uint2 uu; uu.x = u0; uu.y = u1;
      *(uint2*)&P_c[cl * 520 + wv * 130 + tj8 * 16 + rg * 4] = uu;
    }
    #pragma unroll
    for (int w4 = 0; w4 < 4; ++w4) {
      int w = ch * 4 + w4;
      int tjr = (2 * w + (rg >> 1)) & 7;
      bf16x8 pb = *(const bf16x8*)&P_c[cl * 520 + wv * 130 + tjr * 16 + (rg & 1) * 8];
      #pragma unroll
      for (int dt = 0; dt < 4; ++dt) {
        bf16x8 va = *(const bf16x8*)&vf[w * 8192 + dt * 512];
        oacc[dt] = MFMA16(va, pb, oacc[dt], 0, 0, 0);
      }
    }
  }

  // ---- cross-wave O reduction: buf[wv][i][d] ----
  lds_barrier();                                    // all P_c reads done before overwrite
  float* buf = (float*)arena;                       // [4][16][65] (pitch 1040 f32/wave)
  #pragma unroll
  for (int dt = 0; dt < 4; ++dt)
    #pragma unroll
    for (int r = 0; r < 4; ++r)
      buf[wv * 1040 + cl * 65 + dt * 16 + rg * 4 + r] = oacc[dt][r];
  lds_barrier();

  const int i_ = t >> 4, dq = t & 15;
  float o[4];
  #pragma unroll
  for (int k = 0; k < 4; ++k) {
    int d = dq * 4 + k;
    o[k] = buf[0 * 1040 + i_ * 65 + d] + buf[1 * 1040 + i_ * 65 + d]
         + buf[2 * 1040 + i_ * 65 + d] + buf[3 * 1040 + i_ * 65 + d];
  }
  short4 os;
  os.x = f2bf(o[0]); os.y = f2bf(o[1]); os.z = f2bf(o[2]); os.w = f2bf(o[3]);
  // O in-place into qkv Q-slice (this block's own rows x head cols; Q already consumed)
  *(short4*)&qkv[(rowbase + i0 + i_) * QKV_COLS + h * DIM_HEAD + dq * 4] = os;
}

extern "C" void kernel_launch(void* const* d_in, const int* in_sizes, int n_in,
                              void* d_out, int out_size, void* d_ws, size_t ws_size,
                              hipStream_t stream) {
  const float* x    = (const float*)d_in[0];
  const float* Wqkv = (const float*)d_in[1];
  const float* Wout = (const float*)d_in[2];
  const float* bout = (const float*)d_in[3];
  const float* rel  = (const float*)d_in[4];
  const float* sita = (const float*)d_in[5];
  const int*   rpe  = (const int*)d_in[6];

  char* ws = (char*)d_ws;
  short* xb     = (short*)(ws);                 //  8 MB  x bf16 (dead after gemm1)
  short* WqT    = (short*)(ws + 8388608);       //  1.5MB W_qkv^T (dead after gemm1)
  short* WoT    = (short*)(ws + 9961472);       //  0.5MB W_out^T
  short* qkv    = (short*)(ws + 10485760);      // 24 MB  qkv bf16 [8192][1536]; Q-slice becomes O
  short* Kfrag  = (short*)(ws);                 //  8 MB  K fragments (reuses xb)
  short* Vfrag  = (short*)(ws + 35651584);      //  8 MB  V fragments
  float* bias2e = (float*)(ws + 8388608);       // 128 KB exp'd fused bias [8][4096] (reuses WqT)

  float* out1 = (float*)d_out;
  float* out2 = out1 + (size_t)BATCH * N_TOK * DIMM;

  hipLaunchKernelGGL(cvt_bf16_kernel, dim3(4096), dim3(256), 0, stream,
                     x, xb, BATCH * N_TOK * DIMM);
  hipLaunchKernelGGL(tr_cvt_kernel, dim3((512 * 1536 + 255) / 256), dim3(256), 0, stream,
                     Wqkv, WqT, 512, 1536);
  hipLaunchKernelGGL(tr_cvt_kernel, dim3((512 * 512 + 255) / 256), dim3(256), 0, stream,
                     Wout, WoT, 512, 512);
  hipLaunchKernelGGL((gemm_kernel<1, 0>), dim3(12, 64), dim3(256), 0, stream,
                     xb, WqT, (void*)qkv, (const float*)nullptr, 8192, 1536, 512, 512);
  // xb / WqT regions are dead now -> Kfrag / bias2e may overwrite them
  hipLaunchKernelGGL(bias2e_kernel, dim3((HEADS * 4096 + 255) / 256), dim3(256), 0, stream,
                     rel, sita, bias2e);
  hipLaunchKernelGGL(kv_pack_kernel, dim3(24, 64), dim3(256), 0, stream, qkv, Kfrag, Vfrag);
  hipLaunchKernelGGL(attn_kernel, dim3(4096), dim3(256), 0, stream,
                     qkv, Kfrag, Vfrag, bias2e, rpe, out2);
  hipLaunchKernelGGL((gemm_kernel<0, 1>), dim3(4, 64), dim3(256), 0, stream,
                     qkv, WoT, d_out, bout, 8192, 512, 512, 1536);
}

// Round 13
// 158.823 us; speedup vs baseline: 3.7983x; 1.0524x over previous
//
#include <hip/hip_runtime.h>
#include <hip/hip_bf16.h>

typedef __attribute__((ext_vector_type(8))) short bf16x8;
typedef __attribute__((ext_vector_type(4))) float f32x4;
typedef float f32x4u __attribute__((ext_vector_type(4), aligned(4)));  // dword-aligned vec4
typedef __attribute__((ext_vector_type(4))) unsigned int uint32x4;

#define N_TOK 1024
#define HEADS 8
#define DIM_HEAD 64
#define BATCH 8
#define DIMM 512
#define INNER 512
#define QKV_COLS 1536

#define MFMA16 __builtin_amdgcn_mfma_f32_16x16x32_bf16

__device__ inline short f2bf(float f) {
  union { float f; unsigned u; } v;
  v.f = f;
  unsigned r = v.u + 0x7fffu + ((v.u >> 16) & 1u);  // RNE
  return (short)(r >> 16);
}

__device__ inline unsigned pack2bf(float a, float b) {
  return ((unsigned)(unsigned short)f2bf(a)) | (((unsigned)(unsigned short)f2bf(b)) << 16);
}

// LDS-only barrier: orders LDS across waves WITHOUT draining global stores
__device__ inline void lds_barrier() {
  asm volatile("s_waitcnt lgkmcnt(0)" ::: "memory");
  __builtin_amdgcn_s_barrier();
  asm volatile("" ::: "memory");
}

// direct global->LDS 16B/lane (dest = wave-uniform base + lane*16)
__device__ inline void gload_lds16(const short* g, short* l) {
  __builtin_amdgcn_global_load_lds(
      (const __attribute__((address_space(1))) void*)g,
      (__attribute__((address_space(3))) void*)l, 16, 0, 0);
}

// ---------------- merged prep: x->bf16 | Wqkv^T | Wout^T | bias2e ----------------
__global__ __launch_bounds__(256)
void prep_kernel(const float* __restrict__ x, short* __restrict__ xb,
                 const float* __restrict__ Wqkv, short* __restrict__ WqT,
                 const float* __restrict__ Wout, short* __restrict__ WoT,
                 const float* __restrict__ rel, const float* __restrict__ headsita,
                 float* __restrict__ bias2e) {
  const int blk = blockIdx.x, t = threadIdx.x;
  if (blk < 4096) {                      // x fp32 -> bf16 (4M elems, x4/thread)
    int i = (blk * 256 + t) * 4;
    float4 v = *(const float4*)&x[i];
    short4 o;
    o.x = f2bf(v.x); o.y = f2bf(v.y); o.z = f2bf(v.z); o.w = f2bf(v.w);
    *(short4*)&xb[i] = o;
  } else if (blk < 7168) {               // Wqkv [512][1536] -> WqT [1536][512]
    int id = (blk - 4096) * 256 + t;
    int n = id % 1536, k = id / 1536;
    WqT[n * 512 + k] = f2bf(Wqkv[id]);
  } else if (blk < 8192) {               // Wout [512][512] -> WoT [512][512]
    int id = (blk - 7168) * 256 + t;
    int n = id & 511, k = id >> 9;
    WoT[n * 512 + k] = f2bf(Wout[id]);
  } else {                               // bias2e [8][4096]
    int e = (blk - 8192) * 256 + t;
    int h = e >> 12, idx = e & 4095;
    if (idx >= 3969) return;
    int dr = idx / 63 - 31;
    int dc = idx % 63 - 31;
    float th = headsita[h];
    float factor = 1.f / (2.f * th * th + 1e-10f);
    float dis = (float)(dr * dr + dc * dc) * (1.0f / 1024.0f);
    bias2e[e] = __expf(rel[idx * HEADS + h] + 0.01f * __expf(-factor * dis));
  }
}

// ---------------- bf16 MFMA GEMM, m97-style staging ----------------
// SPLIT=1 (gemm1): epilogue writes Q row-major to Qb, K/V directly in MFMA-fragment
// order to Kfrag/Vfrag (addresses = inverse of R11 pack kernel; V merges short4).
// SPLIT=0 (gemm2): float C + bias.
template<int SPLIT>
__global__ __launch_bounds__(256)
void gemm_kernel(const short* __restrict__ A, const short* __restrict__ Bt,
                 void* __restrict__ C, const float* __restrict__ bias,
                 short* __restrict__ Qb, short* __restrict__ Kfrag,
                 short* __restrict__ Vfrag,
                 int M, int Nc, int K, int lda)
{
  __shared__ short Ash[128 * 32];   // linear row-major [128][32] (gload_lds dest)
  __shared__ short Bsh[128 * 32];
  const int t = threadIdx.x;
  const int lane = t & 63, wave = t >> 6;
  const int wm = wave >> 1, wn = wave & 1;
  const int m0 = blockIdx.y * 128, n0 = blockIdx.x * 128;
  const int grow = wave * 32 + (lane >> 2);
  const int gcol = (lane & 3) * 8;
  f32x4 acc[4][4] = {};
  for (int k0 = 0; k0 < K; k0 += 32) {
    lds_barrier();
    #pragma unroll
    for (int i = 0; i < 2; ++i) {
      gload_lds16(&A[(size_t)(m0 + grow + i * 16) * lda + k0 + gcol],
                  &Ash[(wave * 32 + i * 16) * 32]);
      gload_lds16(&Bt[(size_t)(n0 + grow + i * 16) * K + k0 + gcol],
                  &Bsh[(wave * 32 + i * 16) * 32]);
    }
    asm volatile("s_waitcnt vmcnt(0)" ::: "memory");
    __builtin_amdgcn_s_barrier();
    asm volatile("" ::: "memory");
    bf16x8 af[4], bfr[4];
    #pragma unroll
    for (int m = 0; m < 4; ++m)
      af[m] = *(const bf16x8*)&Ash[(wm * 64 + m * 16 + (lane & 15)) * 32 + (lane >> 4) * 8];
    #pragma unroll
    for (int n = 0; n < 4; ++n)
      bfr[n] = *(const bf16x8*)&Bsh[(wn * 64 + n * 16 + (lane & 15)) * 32 + (lane >> 4) * 8];
    #pragma unroll
    for (int m = 0; m < 4; ++m)
      #pragma unroll
      for (int n = 0; n < 4; ++n)
        acc[m][n] = MFMA16(af[m], bfr[n], acc[m][n], 0, 0, 0);
  }
  const int r0 = (lane >> 4) * 4, c0 = lane & 15;
  if (!SPLIT) {
    #pragma unroll
    for (int m = 0; m < 4; ++m)
      #pragma unroll
      for (int n = 0; n < 4; ++n) {
        int col = n0 + wn*64 + n*16 + c0;
        float bv = bias[col];
        #pragma unroll
        for (int r = 0; r < 4; ++r) {
          int row = m0 + wm*64 + m*16 + r0 + r;
          ((float*)C)[(size_t)row * Nc + col] = acc[m][n][r] + bv;
        }
      }
  } else {
    const int seg = n0 >> 9;   // 0=Q, 1=K, 2=V (each 512 cols = 4 blocks)
    #pragma unroll
    for (int m = 0; m < 4; ++m)
      #pragma unroll
      for (int n = 0; n < 4; ++n) {
        const int colg = n0 + wn*64 + n*16 + c0;
        const int rowg0 = m0 + wm*64 + m*16 + r0;
        if (seg == 0) {
          #pragma unroll
          for (int rr = 0; rr < 4; ++rr)
            Qb[(size_t)(rowg0 + rr) * 512 + colg] = f2bf(acc[m][n][rr]);
        } else if (seg == 1) {
          // K: element (j, d=f*32+rg*8+e) -> Kfrag[((bh*16+tj)*8 + wvk*2+f)*512 + (rg*16+clk)*8 + e]
          const int d = colg - 512, h = d >> 6, dd = d & 63;
          const int b = rowg0 >> 10, j0 = rowg0 & 1023;
          const size_t base = ((((size_t)(b * 8 + h) * 16 + (j0 >> 6)) * 8)
                               + ((j0 >> 4) & 3) * 2 + (dd >> 5)) * 512
                              + ((dd >> 3) & 3) * 128 + (dd & 7);
          #pragma unroll
          for (int rr = 0; rr < 4; ++rr)
            Kfrag[base + ((j0 + rr) & 15) * 8] = f2bf(acc[m][n][rr]);
        } else {
          // V: element (j, d) -> Vfrag[((bh*8+w)*16 + wvv*4+dt)*512 + (rgv*16+clv)*8 + e]
          // 4 consecutive rows = 4 consecutive e -> one short4 store
          const int d = colg - 1024, h = d >> 6, dd = d & 63;
          const int b = rowg0 >> 10, j0 = rowg0 & 1023;
          const int w = j0 >> 7, j7 = j0 & 127;
          const int rgv = (((j7 >> 6) & 1) << 1) | ((j7 >> 3) & 1);
          const int wvv = (j7 >> 4) & 3, e0 = j7 & 7;   // e0 in {0,4}
          const size_t addr = (((size_t)(b * 8 + h) * 8 + w) * 16 + wvv * 4 + (dd >> 4)) * 512
                              + (rgv * 16 + (dd & 15)) * 8 + e0;
          short4 sv;
          sv.x = f2bf(acc[m][n][0]); sv.y = f2bf(acc[m][n][1]);
          sv.z = f2bf(acc[m][n][2]); sv.w = f2bf(acc[m][n][3]);
          *(short4*)&Vfrag[addr] = sv;
        }
      }
  }
}

// ---------------- fused attention v13: R12 structure, Qbuf stride 512 ----------------
__global__ __launch_bounds__(256, 4)
void attn_kernel(short* Qb,                           // NOT restrict: O aliases Q
                 const short* __restrict__ Kfrag,
                 const short* __restrict__ Vfrag,
                 const float* __restrict__ bias2e,    // [8][4096]
                 const int* __restrict__ rpe_p,
                 float* __restrict__ out2)            // softmax(dots0) [B,H,N,N]
{
  __shared__ __align__(16) char arena[17408];  // stage[256*17]f32 | P_c[16][520]bf16 | buf
  __shared__ float red0[4][16];
  __shared__ float red1[4][16];

  const int t = threadIdx.x;
  const int lane = t & 63, wv = t >> 6;
  const int rg = lane >> 4, cl = lane & 15;

  const int id = blockIdx.x;                 // XCD-swizzled (bijective)
  const int bh = (id & 7) * 8 + ((id >> 3) & 7);
  const int i0 = (id >> 6) * 16;
  const int b = bh >> 3, h = bh & 7;
  const size_t rowbase = (size_t)b * N_TOK;

  // ---- Q fragments ----
  const size_t qoff = (rowbase + i0 + cl) * 512 + h * DIM_HEAD;
  const bf16x8 qf0 = *(const bf16x8*)&Qb[qoff + rg * 8];
  const bf16x8 qf1 = *(const bf16x8*)&Qb[qoff + 32 + rg * 8];

  // ---- QK^T (swapped), lane-linear fragment loads ----
  const short* kf = Kfrag + (((size_t)bh * 16) * 8 + wv * 2) * 512 + lane * 8;
  f32x4 sc[16];
  bf16x8 a0 = *(const bf16x8*)&kf[0];
  bf16x8 a1 = *(const bf16x8*)&kf[512];
  #pragma unroll
  for (int tj = 0; tj < 16; ++tj) {
    bf16x8 n0, n1;
    if (tj < 15) {
      n0 = *(const bf16x8*)&kf[(tj + 1) * 4096];
      n1 = *(const bf16x8*)&kf[(tj + 1) * 4096 + 512];
    }
    f32x4 z = (f32x4){0.f, 0.f, 0.f, 0.f};
    z = MFMA16(a0, qf0, z, 0, 0, 0);
    z = MFMA16(a1, qf1, z, 0, 0, 0);
    sc[tj] = z;
    a0 = n0; a1 = n1;
  }

  // ---- softmax0 on RAW scores (scale folded into exp arg) ----
  float m = -1e30f;
  #pragma unroll
  for (int tj = 0; tj < 16; ++tj)
    #pragma unroll
    for (int r = 0; r < 4; ++r) m = fmaxf(m, sc[tj][r]);
  m = fmaxf(m, __shfl_xor(m, 16));
  m = fmaxf(m, __shfl_xor(m, 32));
  if (lane < 16) red0[wv][lane] = m;
  lds_barrier();
  m = fmaxf(fmaxf(red0[0][cl], red0[1][cl]), fmaxf(red0[2][cl], red0[3][cl]));

  float s = 0.f;
  #pragma unroll
  for (int tj = 0; tj < 16; ++tj)
    #pragma unroll
    for (int r = 0; r < 4; ++r) {
      float e = __expf((sc[tj][r] - m) * 0.125f);
      sc[tj][r] = e;
      s += e;
    }
  s += __shfl_xor(s, 16);
  s += __shfl_xor(s, 32);
  if (lane < 16) red1[wv][lane] = s;
  lds_barrier();
  const float sm0 = red1[0][cl] + red1[1][cl] + red1[2][cl] + red1[3][cl];
  const float iv0 = 1.f / sm0;

  // ---- out2 via LDS transpose chunks, full-line stores ----
  float* stage = (float*)arena;                    // [256][17] f32
  const size_t o2base = ((size_t)(b * HEADS + h) * N_TOK + i0) * N_TOK;
  #pragma unroll
  for (int c = 0; c < 4; ++c) {
    #pragma unroll
    for (int tjl = 0; tjl < 4; ++tjl)
      #pragma unroll
      for (int r = 0; r < 4; ++r)
        stage[(tjl * 64 + wv * 16 + rg * 4 + r) * 17 + cl] = sc[c * 4 + tjl][r] * iv0;
    lds_barrier();
    #pragma unroll
    for (int k = 0; k < 4; ++k) {
      int row = wv * 4 + k;
      #pragma unroll
      for (int e = 0; e < 4; ++e) {
        float v = stage[(e * 64 + lane) * 17 + row];
        out2[o2base + (size_t)row * N_TOK + c * 256 + e * 64 + lane] = v;
      }
    }
    lds_barrier();
  }

  // ---- P = e0 * exp(bias) / sum1 -- vectorized affine-idx loads ----
  const int i_row = i0 + cl;
  const int ri = i_row >> 5, ci = i_row & 31;
  float iv1;
  if (rpe_p[0]) {
    const float* bt = bias2e + (h << 12);        // [h][4096]
    const int C = (ri - (wv >> 1)) * 63 + ci - ((wv & 1) * 16 + rg * 4) + 1984;
    float s1 = 0.f;
    #pragma unroll
    for (int tj = 0; tj < 16; ++tj) {
      f32x4u bv = *(const f32x4u*)&bt[C - tj * 126 - 3];   // [r3, r2, r1, r0]
      float v0 = sc[tj][0] * bv[3];
      float v1 = sc[tj][1] * bv[2];
      float v2 = sc[tj][2] * bv[1];
      float v3 = sc[tj][3] * bv[0];
      sc[tj][0] = v0; sc[tj][1] = v1; sc[tj][2] = v2; sc[tj][3] = v3;
      s1 += (v0 + v1) + (v2 + v3);
    }
    s1 += __shfl_xor(s1, 16);
    s1 += __shfl_xor(s1, 32);
    if (lane < 16) red0[wv][lane] = s1;
    lds_barrier();
    iv1 = 1.f / (red0[0][cl] + red0[1][cl] + red0[2][cl] + red0[3][cl]);
  } else {
    iv1 = iv0;
  }

  // ---- chunked P pack + PV (wave-private half-passes) ----
  unsigned short* P_c = (unsigned short*)arena;    // [16 i][4 wv x 130] pitch 520
  const short* vf = Vfrag + (((size_t)bh * 8) * 16 + wv * 4) * 512 + lane * 8;
  f32x4 oacc[4];
  #pragma unroll
  for (int dt = 0; dt < 4; ++dt) oacc[dt] = (f32x4){0.f, 0.f, 0.f, 0.f};
  #pragma unroll
  for (int ch = 0; ch < 2; ++ch) {
    #pragma unroll
    for (int tj8 = 0; tj8 < 8; ++tj8) {
      int tj = ch * 8 + tj8;
      unsigned u0 = pack2bf(sc[tj][0] * iv1, sc[tj][1] * iv1);
      unsigned u1 = pack2bf(sc[tj][2] * iv1, sc[tj][3] * iv1);
      uint2 uu; uu.x = u0; uu.y = u1;
      *(uint2*)&P_c[cl * 520 + wv * 130 + tj8 * 16 + rg * 4] = uu;
    }
    #pragma unroll
    for (int w4 = 0; w4 < 4; ++w4) {
      int w = ch * 4 + w4;
      int tjr = (2 * w + (rg >> 1)) & 7;
      bf16x8 pb = *(const bf16x8*)&P_c[cl * 520 + wv * 130 + tjr * 16 + (rg & 1) * 8];
      #pragma unroll
      for (int dt = 0; dt < 4; ++dt) {
        bf16x8 va = *(const bf16x8*)&vf[w * 8192 + dt * 512];
        oacc[dt] = MFMA16(va, pb, oacc[dt], 0, 0, 0);
      }
    }
  }

  // ---- cross-wave O reduction ----
  lds_barrier();
  float* buf = (float*)arena;                       // [4][16][65]
  #pragma unroll
  for (int dt = 0; dt < 4; ++dt)
    #pragma unroll
    for (int r = 0; r < 4; ++r)
      buf[wv * 1040 + cl * 65 + dt * 16 + rg * 4 + r] = oacc[dt][r];
  lds_barrier();

  const int i_ = t >> 4, dq = t & 15;
  float o[4];
  #pragma unroll
  for (int k = 0; k < 4; ++k) {
    int d = dq * 4 + k;
    o[k] = buf[0 * 1040 + i_ * 65 + d] + buf[1 * 1040 + i_ * 65 + d]
         + buf[2 * 1040 + i_ * 65 + d] + buf[3 * 1040 + i_ * 65 + d];
  }
  short4 os;
  os.x = f2bf(o[0]); os.y = f2bf(o[1]); os.z = f2bf(o[2]); os.w = f2bf(o[3]);
  *(short4*)&Qb[(rowbase + i0 + i_) * 512 + h * DIM_HEAD + dq * 4] = os;  // O in-place
}

extern "C" void kernel_launch(void* const* d_in, const int* in_sizes, int n_in,
                              void* d_out, int out_size, void* d_ws, size_t ws_size,
                              hipStream_t stream) {
  const float* x    = (const float*)d_in[0];
  const float* Wqkv = (const float*)d_in[1];
  const float* Wout = (const float*)d_in[2];
  const float* bout = (const float*)d_in[3];
  const float* rel  = (const float*)d_in[4];
  const float* sita = (const float*)d_in[5];
  const int*   rpe  = (const int*)d_in[6];

  char* ws = (char*)d_ws;
  short* xb     = (short*)(ws);                 //  8 MB  x bf16
  short* WqT    = (short*)(ws + 8388608);       //  1.5MB W_qkv^T
  short* WoT    = (short*)(ws + 9961472);       //  0.5MB W_out^T
  short* Qbuf   = (short*)(ws + 10485760);      //  8 MB  Q [8192][512]; becomes O in-place
  short* Kfrag  = (short*)(ws + 18874368);      //  8 MB  K fragments
  float* bias2e = (float*)(ws + 27262976);      // 128 KB exp'd fused bias [8][4096]
  short* Vfrag  = (short*)(ws + 35651584);      //  8 MB  V fragments

  float* out1 = (float*)d_out;
  float* out2 = out1 + (size_t)BATCH * N_TOK * DIMM;

  hipLaunchKernelGGL(prep_kernel, dim3(8320), dim3(256), 0, stream,
                     x, xb, Wqkv, WqT, Wout, WoT, rel, sita, bias2e);
  hipLaunchKernelGGL((gemm_kernel<1>), dim3(12, 64), dim3(256), 0, stream,
                     xb, WqT, (void*)nullptr, (const float*)nullptr,
                     Qbuf, Kfrag, Vfrag, 8192, 1536, 512, 512);
  hipLaunchKernelGGL(attn_kernel, dim3(4096), dim3(256), 0, stream,
                     Qbuf, Kfrag, Vfrag, bias2e, rpe, out2);
  hipLaunchKernelGGL((gemm_kernel<0>), dim3(4, 64), dim3(256), 0, stream,
                     Qbuf, WoT, d_out, bout,
                     (short*)nullptr, (short*)nullptr, (short*)nullptr, 8192, 512, 512, 512);
}